// Round 6
// baseline (762.553 us; speedup 1.0000x reference)
//
#include <hip/hip_runtime.h>
#include <hip/hip_fp16.h>
#include <math.h>

// DiagonalLSTM: B=8, Cin=HID=128, H=64, W=64, K=2, T = 2W-1 = 127 steps.
//
// Round 20 design (round 19 + M-split to 64 blocks):
//   - lstm runs on 64 blocks x 256 thr (4 waves): each block computes a
//     64-unit half (mh) of z/h for its 16 cells. Per-CU per-step work
//     halves; LDS read volume quarters (4 own-k ds_read_b128/thread).
//   - partner h half arrives via hp[] global buffer (sentinel u64 per
//     thread, fire-and-forget, hx-style) loaded DIRECTLY into MFMA
//     B-fragments (no LDS round-trip): tid_p = 128j + 32*quad + 16s +
//     (2*cell+bl). Own-k MFMAs run first; partner data validated ~35%
//     into the step (0.55-step grace after producer's store).
//   - hp slot 0 holds zeros = h(-1); producers write h(T) to slot T+1.
//   - blockIdx map rgr=blk&7, mh=(blk>>3)&1, bg=blk>>4 puts mh-partners
//     8 apart (same XCD under round-robin).
//   - hx boundary protocol kept (R19 lazy load), own-half lanes only.
//   - tier-2: if ws too small for hp, fall back to the R19 32-block
//     kernel verbatim; tier-3: round-1 fallback.

#define HID 128
#define BB 8
#define HH 64
#define WW 64
#define TT 127

#define HROW 136                 // padded LDS row stride in halfs
#define HPSTEP (64 * 256)        // hp u64s per step slot

// prep item counts (uint4/scalar units):
//   wp frags 131072 | zph bias 512 | hx fill 130048 (uint4)
//   | hp fill 1048576 (uint4: 8192 zero + rest sentinel)
#define NPREP64 5118             // (261632 + 1048576) / 256
#define NPREP32 1022             // 261632 / 256

typedef _Float16 v8h __attribute__((ext_vector_type(8)));
typedef float v4f __attribute__((ext_vector_type(4)));

#define SENT64 0xFFFFFFFFFFFFFFFFULL  // 4x f16 -NaN (0xFF fill pattern)

__device__ __forceinline__ float fsig(float x) {
  float e = __builtin_amdgcn_exp2f(x * -1.44269504f);
  return __builtin_amdgcn_rcpf(1.f + e);
}
__device__ __forceinline__ float ftanh_(float x) {
  float e = __builtin_amdgcn_exp2f(x * 2.88539009f);
  return __builtin_fmaf(-2.f, __builtin_amdgcn_rcpf(1.f + e), 1.f);
}

// ---- merged prep + zpre kernel (nprep = prep block count) ----
__global__ __launch_bounds__(256) void prep_zpre(
    const float* __restrict__ x, const float* __restrict__ w_is,
    const float* __restrict__ b_is, const float* __restrict__ b_ss,
    const float* __restrict__ w_ss, _Float16* __restrict__ wp,
    __half* __restrict__ zph, unsigned long long* __restrict__ hx,
    unsigned long long* __restrict__ hp, int nprep) {
  const int bid = blockIdx.x;
  const int tid = threadIdx.x;

  __shared__ _Float16 xt[64][136];  // zpre half only

  if (bid < nprep) {
    int idx = bid * 256 + tid;
    if (idx < 131072) {
      // w_ss -> Wcat(512x256) A-frags: wp[(((mt*8+kt)*64+L)*8+j)]
      int j = idx & 7;
      int L = (idx >> 3) & 63;
      int kt = (idx >> 9) & 7;
      int mt = idx >> 12;
      int O = mt * 16 + (L & 15);
      int k = kt * 32 + ((L >> 4) & 3) * 8 + j;
      float v = (k < 128) ? w_ss[(size_t)O * 256 + k * 2]
                          : w_ss[(size_t)O * 256 + (k - 128) * 2 + 1];
      wp[idx] = (_Float16)v;
    } else if (idx < 131584) {
      int idx2 = idx - 131072;  // 0..511
      int g = (idx2 >> 2) & 3;
      int u = (idx2 >> 4) * 4 + (idx2 & 3);
      int O = g * 128 + u;
      zph[(size_t)BB * HH * WW * 512 + idx2] = __float2half(b_is[O] + b_ss[O]);
    } else if (idx < 261632) {
      // hx sentinel fill: 260096 u64 as 130048 x 16B
      int j = idx - 131584;
      uint4 s;
      s.x = 0xFFFFFFFFu; s.y = 0xFFFFFFFFu;
      s.z = 0xFFFFFFFFu; s.w = 0xFFFFFFFFu;
      ((uint4*)hx)[j] = s;
    } else {
      // hp fill: slot 0 (= h(-1)) zeros, slots 1..TT sentinel
      int j = idx - 261632;  // 0..1048575 uint4
      uint4 s;
      if (j < 8192) { s.x = 0u; s.y = 0u; s.z = 0u; s.w = 0u; }
      else { s.x = 0xFFFFFFFFu; s.y = 0xFFFFFFFFu;
             s.z = 0xFFFFFFFFu; s.w = 0xFFFFFFFFu; }
      ((uint4*)hp)[j] = s;
    }
    return;
  }

  // ---------------- zpre half ----------------
  const int zb = bid - nprep;  // 0..511
  const int b = zb >> 6;
  const int r = zb & 63;
  const int wv = tid >> 6;
  const int L = tid & 63;
  const int quad = L >> 4;
  const int l15 = L & 15;

  {
    const int cw = tid >> 4;
    const int w4 = (tid & 15) * 4;
#pragma unroll
    for (int p = 0; p < 8; p++) {
      int c = p * 16 + cw;
      float4 v = *(const float4*)&x[(((size_t)b * 128 + c) * HH + r) * WW + w4];
      xt[w4 + 0][c] = (_Float16)v.x;
      xt[w4 + 1][c] = (_Float16)v.y;
      xt[w4 + 2][c] = (_Float16)v.z;
      xt[w4 + 3][c] = (_Float16)v.w;
    }
  }

  v8h wfr[8][4];
  float4 bv[8];
#pragma unroll
  for (int m = 0; m < 8; m++) {
    const int mt = 8 * wv + m;
    const int O = mt * 16 + l15;
#pragma unroll
    for (int kt = 0; kt < 4; kt++) {
      const float* p = w_is + (size_t)O * 128 + kt * 32 + quad * 8;
      float4 a = *(const float4*)p;
      float4 b2 = *(const float4*)(p + 4);
      v8h f;
      f[0] = (_Float16)a.x;  f[1] = (_Float16)a.y;
      f[2] = (_Float16)a.z;  f[3] = (_Float16)a.w;
      f[4] = (_Float16)b2.x; f[5] = (_Float16)b2.y;
      f[6] = (_Float16)b2.z; f[7] = (_Float16)b2.w;
      wfr[m][kt] = f;
    }
    const int O4 = mt * 16 + quad * 4;
    float4 bi = *(const float4*)&b_is[O4];
    float4 bs4 = *(const float4*)&b_ss[O4];
    bv[m] = make_float4(bi.x + bs4.x, bi.y + bs4.y, bi.z + bs4.z, bi.w + bs4.w);
  }

  __syncthreads();

#pragma unroll
  for (int nt = 0; nt < 4; nt++) {
    v8h bf[4];
#pragma unroll
    for (int kt = 0; kt < 4; kt++)
      bf[kt] = *(const v8h*)&xt[nt * 16 + l15][kt * 32 + quad * 8];
    const size_t pos = ((size_t)b * HH + r) * WW + nt * 16 + l15;
#pragma unroll
    for (int m = 0; m < 8; m++) {
      v4f acc = (v4f){0.f, 0.f, 0.f, 0.f};
#pragma unroll
      for (int kt = 0; kt < 4; kt++)
        acc = __builtin_amdgcn_mfma_f32_16x16x32_f16(wfr[m][kt], bf[kt], acc,
                                                     0, 0, 0);
      __half2 lo = __floats2half2_rn(acc[0] + bv[m].x, acc[1] + bv[m].y);
      __half2 hi = __floats2half2_rn(acc[2] + bv[m].z, acc[3] + bv[m].w);
      uint2 pk;
      pk.x = *(unsigned*)&lo;
      pk.y = *(unsigned*)&hi;
      *(uint2*)&zph[pos * 512 + (m * 4 + quad) * 16 + wv * 4] = pk;
    }
  }
}

// Step barrier: LDS-visibility only (no vmcnt drain; see R15 notes).
#define STEP_BARRIER()                                   \
  do {                                                   \
    asm volatile("s_waitcnt lgkmcnt(0)" ::: "memory");   \
    __builtin_amdgcn_s_barrier();                        \
    asm volatile("" ::: "memory");                       \
  } while (0)

#define HPLD(p) __hip_atomic_load((p), __ATOMIC_RELAXED, __HIP_MEMORY_SCOPE_AGENT)

// ============ 64-block M-split step body ============
#define STEP64(T, RB)                                                          \
  do {                                                                         \
    /* own-k LDS B-frags (4 x b128) right after barrier */                     \
    v8h f0a = *(const v8h*)&h_lds[RB][(rl * 2 + bl) * HROW + oa * 32 +         \
                                      quad * 8];                               \
    v8h f0b = *(const v8h*)&h_lds[RB][(rl * 2 + bl) * HROW + (oa + 1) * 32 +   \
                                      quad * 8];                               \
    v8h f1a = *(const v8h*)&h_lds[RB][((rl + 1) * 2 + bl) * HROW + oa * 32 +   \
                                      quad * 8];                               \
    v8h f1b = *(const v8h*)&h_lds[RB][((rl + 1) * 2 + bl) * HROW +             \
                                      (oa + 1) * 32 + quad * 8];               \
    /* partner B-frag u64 loads: h(T-1) = hp slot T */                         \
    unsigned long long P0a = HPLD(hpq + o0);                                   \
    unsigned long long P0b = HPLD(hpq + o0 + 16);                              \
    unsigned long long P0c = HPLD(hpq + o0 + 128);                             \
    unsigned long long P0d = HPLD(hpq + o0 + 144);                             \
    unsigned long long P1a = HPLD(hpq + o1);                                   \
    unsigned long long P1b = HPLD(hpq + o1 + 16);                              \
    unsigned long long P1c = HPLD(hpq + o1 + 128);                             \
    unsigned long long P1d = HPLD(hpq + o1 + 144);                             \
    if (!p0v) { P0a = 0ull; P0b = 0ull; P0c = 0ull; P0d = 0ull; }              \
    /* convert zu -> v4f (chain-1 C-operand init) */                           \
    v4f zi[4];                                                                 \
    _Pragma("unroll") for (int g = 0; g < 4; g++)                              \
        _Pragma("unroll") for (int i = 0; i < 4; i++)                          \
        zi[g][i] = __half2float(zu.h[g * 4 + i]);                              \
    /* zp prefetch for T+1 */                                                  \
    {                                                                          \
      const uint4* p = (const uint4*)(((unsigned)wn < WW) ? zcur : zbias);     \
      zu.q[0] = p[0];                                                          \
      zu.q[1] = p[1];                                                          \
      wn++;                                                                    \
      zcur += 512;                                                             \
    }                                                                          \
    /* own-k MFMA (16) */                                                      \
    v4f acc0[4], acc1[4];                                                      \
    _Pragma("unroll") for (int g = 0; g < 4; g++) {                            \
      acc0[g] = (v4f){0.f, 0.f, 0.f, 0.f};                                     \
      acc1[g] = zi[g];                                                         \
    }                                                                          \
    _Pragma("unroll") for (int g = 0; g < 4; g++)                              \
        acc0[g] = __builtin_amdgcn_mfma_f32_16x16x32_f16(wfrag[g][oa], f0a,    \
                                                         acc0[g], 0, 0, 0);    \
    _Pragma("unroll") for (int g = 0; g < 4; g++)                              \
        acc0[g] = __builtin_amdgcn_mfma_f32_16x16x32_f16(wfrag[g][oa + 1],     \
                                                         f0b, acc0[g], 0, 0,   \
                                                         0);                   \
    _Pragma("unroll") for (int g = 0; g < 4; g++)                              \
        acc1[g] = __builtin_amdgcn_mfma_f32_16x16x32_f16(wfrag[g][4 + oa],     \
                                                         f1a, acc1[g], 0, 0,   \
                                                         0);                   \
    _Pragma("unroll") for (int g = 0; g < 4; g++)                              \
        acc1[g] = __builtin_amdgcn_mfma_f32_16x16x32_f16(wfrag[g][5 + oa],     \
                                                         f1b, acc1[g], 0, 0,   \
                                                         0);                   \
    /* validate partner data (rare spin in steady state) */                    \
    while (__ballot(P0a == SENT64 || P0b == SENT64 || P0c == SENT64 ||         \
                    P0d == SENT64 || P1a == SENT64 || P1b == SENT64 ||         \
                    P1c == SENT64 || P1d == SENT64) != 0ull) {                 \
      __builtin_amdgcn_s_sleep(1);                                             \
      P0a = HPLD(hpq + o0);                                                    \
      P0b = HPLD(hpq + o0 + 16);                                               \
      P0c = HPLD(hpq + o0 + 128);                                              \
      P0d = HPLD(hpq + o0 + 144);                                              \
      P1a = HPLD(hpq + o1);                                                    \
      P1b = HPLD(hpq + o1 + 16);                                               \
      P1c = HPLD(hpq + o1 + 128);                                              \
      P1d = HPLD(hpq + o1 + 144);                                              \
      if (!p0v) { P0a = 0ull; P0b = 0ull; P0c = 0ull; P0d = 0ull; }            \
    }                                                                          \
    /* partner MFMA (16) */                                                    \
    {                                                                          \
      union U2 { unsigned long long q[2]; v8h v; } uu;                         \
      uu.q[0] = P0a; uu.q[1] = P0b; v8h g0a = uu.v;                            \
      uu.q[0] = P0c; uu.q[1] = P0d; v8h g0b = uu.v;                            \
      uu.q[0] = P1a; uu.q[1] = P1b; v8h g1a = uu.v;                            \
      uu.q[0] = P1c; uu.q[1] = P1d; v8h g1b = uu.v;                            \
      _Pragma("unroll") for (int g = 0; g < 4; g++)                            \
          acc0[g] = __builtin_amdgcn_mfma_f32_16x16x32_f16(wfrag[g][pa], g0a,  \
                                                           acc0[g], 0, 0, 0);  \
      _Pragma("unroll") for (int g = 0; g < 4; g++)                            \
          acc0[g] = __builtin_amdgcn_mfma_f32_16x16x32_f16(wfrag[g][pa + 1],   \
                                                           g0b, acc0[g], 0, 0, \
                                                           0);                 \
      _Pragma("unroll") for (int g = 0; g < 4; g++)                            \
          acc1[g] = __builtin_amdgcn_mfma_f32_16x16x32_f16(wfrag[g][4 + pa],   \
                                                           g1a, acc1[g], 0, 0, \
                                                           0);                 \
      _Pragma("unroll") for (int g = 0; g < 4; g++)                            \
          acc1[g] = __builtin_amdgcn_mfma_f32_16x16x32_f16(wfrag[g][5 + pa],   \
                                                           g1b, acc1[g], 0, 0, \
                                                           0);                 \
    }                                                                          \
    /* mid-step hx boundary load (R19 lazy) */                                 \
    unsigned long long pend = 0ull;                                            \
    if (cact) pend = HPLD(ca);                                                 \
    /* gates */                                                                \
    const int w = (T)-r;                                                       \
    const bool inband = ((unsigned)w < WW);                                    \
    float hv[4];                                                               \
    _Pragma("unroll") for (int rg2 = 0; rg2 < 4; rg2++) {                      \
      float z0 = acc0[0][rg2] + acc1[0][rg2];                                  \
      float z1 = acc0[1][rg2] + acc1[1][rg2];                                  \
      float z2 = acc0[2][rg2] + acc1[2][rg2];                                  \
      float z3 = acc0[3][rg2] + acc1[3][rg2];                                  \
      float iv = fsig(z0);                                                     \
      float fv = fsig(z1);                                                     \
      float ov = fsig(z2);                                                     \
      float gv = ftanh_(z3);                                                   \
      c[rg2] = fv * c[rg2] + iv * gv;                                          \
      hv[rg2] = ov * ftanh_(c[rg2]);                                           \
    }                                                                          \
    /* pack; own h -> LDS wb; hp export (all threads); hx export */            \
    __half2 plo = __floats2half2_rn(hv[0], hv[1]);                             \
    __half2 phi = __floats2half2_rn(hv[2], hv[3]);                             \
    unsigned long long pk64 =                                                  \
        ((unsigned long long)*(unsigned*)&phi << 32) | *(unsigned*)&plo;       \
    {                                                                          \
      uint2 pk;                                                                \
      pk.x = *(unsigned*)&plo;                                                 \
      pk.y = *(unsigned*)&phi;                                                 \
      *(uint2*)&h_lds[(RB) ^ 1][((rl + 1) * 2 + bl) * HROW + uq0] = pk;        \
    }                                                                          \
    __hip_atomic_store(hpe, pk64, __ATOMIC_RELAXED, __HIP_MEMORY_SCOPE_AGENT); \
    hpe += HPSTEP;                                                             \
    if (rgr < 7 && l15 >= 14)                                                  \
      __hip_atomic_store(pa_hx, pk64, __ATOMIC_RELAXED,                        \
                         __HIP_MEMORY_SCOPE_AGENT);                            \
    pa_hx += 2048;                                                             \
    /* out shift-window */                                                     \
    _Pragma("unroll") for (int rg2 = 0; rg2 < 4; rg2++) {                      \
      outb[rg2].x = outb[rg2].y;                                               \
      outb[rg2].y = outb[rg2].z;                                               \
      outb[rg2].z = outb[rg2].w;                                               \
      outb[rg2].w = hv[rg2];                                                   \
    }                                                                          \
    if (inband && (w & 3) == 3) {                                              \
      *(float4*)op0 = outb[0];                                                 \
      *(float4*)op1 = outb[1];                                                 \
      *(float4*)op2 = outb[2];                                                 \
      *(float4*)op3 = outb[3];                                                 \
      op0 += 4; op1 += 4; op2 += 4; op3 += 4;                                  \
    }                                                                          \
    /* hx validate (own-half lanes) -> wb slot 0 */                            \
    if (is_cons) {                                                             \
      while (__ballot(cact && (pend == SENT64)) != 0ull) {                     \
        __builtin_amdgcn_s_sleep(1);                                           \
        if (cact) pend = HPLD(ca);                                             \
      }                                                                        \
      if (cact)                                                                \
        *(unsigned long long*)&h_lds[(RB) ^ 1][(0 * 2 + ebl) * HROW + eu] =    \
            pend;                                                              \
    }                                                                          \
    ca += 2048;                                                                \
    hpq += HPSTEP;                                                             \
    STEP_BARRIER();                                                            \
  } while (0)

__global__ __launch_bounds__(256, 1) void lstm_mfma64(
    const __half* __restrict__ zph, const _Float16* __restrict__ wp,
    unsigned long long* __restrict__ hx, unsigned long long* __restrict__ hp,
    float* __restrict__ out) {
  const int blk = blockIdx.x;      // 0..63
  const int rgr = blk & 7;         // row group (partner pairs 8 apart: same XCD)
  const int mh = (blk >> 3) & 1;   // unit half
  const int bg = blk >> 4;         // batch group 0..3
  const int R0 = rgr * 8;
  const int tid = threadIdx.x;
  const int wv = tid >> 6;         // 0..3
  const int L = tid & 63;
  const int quad = L >> 4;
  const int l15 = L & 15;
  const int rl = l15 >> 1;
  const int bl = l15 & 1;
  const int b = bg * 2 + bl;
  const int r = R0 + rl;
  const int uq0 = mh * 64 + 16 * wv + quad * 4;
  const int ug = uq0 >> 2;         // 16*mh + 4*wv + quad
  const int zoff = ug * 16;
  const int oa = 2 * mh;           // own-k kt pair base
  const int pa = 2 * (1 - mh);     // partner kt pair base

  __shared__ _Float16 h_lds[2][9 * 2 * HROW];
  for (int i = tid; i < (2 * 9 * 2 * HROW) / 2; i += 256)
    ((unsigned*)h_lds)[i] = 0u;

  // weights as A-fragments: mt = 8g + 4*mh + wv
  v8h wfrag[4][8];
  {
    const v8h* wp8 = (const v8h*)wp;
#pragma unroll
    for (int g = 0; g < 4; g++)
#pragma unroll
      for (int kt = 0; kt < 8; kt++)
        wfrag[g][kt] = wp8[((size_t)((8 * g + 4 * mh + wv) * 8 + kt)) * 64 + L];
  }

  float c[4] = {0.f, 0.f, 0.f, 0.f};
  float4 outb[4];
#pragma unroll
  for (int i = 0; i < 4; i++) outb[i] = make_float4(0.f, 0.f, 0.f, 0.f);

  // hx boundary (own-half lanes only)
  const bool is_cons = (wv == 0) && (rgr > 0);
  const bool cact = is_cons && (((L >> 4) & 1) == mh);
  const int ebl = L >> 5;
  const int eu = (L & 31) * 4;
  const int exp_idx = bl * 32 + ug;  // producer slot (l15>=14)
  const unsigned long long* ca =
      hx + (((size_t)(rgr > 0 ? rgr - 1 : 0) * 4 + bg)) * 64 + L;
  unsigned long long* pa_hx = hx + (((size_t)rgr * 4 + bg)) * 64 + exp_idx;

  // hp exchange: partner = blk^8 (mh toggle); chain0 cell rl-1 (prev rgr
  // block blk^8-1 when rl==0); consumer offsets o0/o1; producer hpe.
  const int pblk1 = blk ^ 8;
  const int pblk0 = (rl > 0) ? pblk1 : ((rgr > 0) ? pblk1 - 1 : pblk1);
  const bool p0v = (rl > 0) || (rgr > 0);  // else h(-1)=0 fragments
  const int l15c0 = 2 * ((rl - 1) & 7) + bl;
  const int l15c1 = 2 * rl + bl;
  const int o0 = pblk0 * 256 + quad * 32 + l15c0;
  const int o1 = pblk1 * 256 + quad * 32 + l15c1;
  const unsigned long long* hpq = hp;  // step T reads slot T (= h(T-1))
  unsigned long long* hpe = hp + (size_t)HPSTEP + (size_t)blk * 256 + tid;

  // incremental pointers
  const __half* zpp = zph + ((size_t)b * HH + r) * WW * 512 + zoff;
  const __half* zbias = zph + (size_t)BB * HH * WW * 512 + zoff;
  float* op0 = out + (((size_t)b * HID + uq0 + 0) * HH + r) * WW;
  float* op1 = out + (((size_t)b * HID + uq0 + 1) * HH + r) * WW;
  float* op2 = out + (((size_t)b * HID + uq0 + 2) * HH + r) * WW;
  float* op3 = out + (((size_t)b * HID + uq0 + 3) * HH + r) * WW;

  union ZU {
    uint4 q[2];
    __half h[16];
  } zu;
  {
    const uint4* p0 = (const uint4*)((r == 0) ? zpp : zbias);
    zu.q[0] = p0[0];
    zu.q[1] = p0[1];
  }
  int wn = 1 - r;
  const __half* zcur = zpp + (ptrdiff_t)wn * 512;

  __syncthreads();

  for (int t = 0; t < TT - 1; t += 2) {
    STEP64(t, 0);
    STEP64(t + 1, 1);
  }
  STEP64(TT - 1, 0);
}

// ============ tier-2: R19 32-block kernel (verbatim) ============
#define STEP_BODY(T, RB)                                                       \
  do {                                                                         \
    v8h bfr[4];                                                                \
    _Pragma("unroll") for (int kt = 0; kt < 4; kt++)                           \
        bfr[kt] = *(const v8h*)&h_lds[RB][(rl * 2 + bl) * HROW + kt * 32 +     \
                                          quad * 8];                           \
    v4f zi[4];                                                                 \
    _Pragma("unroll") for (int g = 0; g < 4; g++)                              \
        _Pragma("unroll") for (int i = 0; i < 4; i++)                          \
        zi[g][i] = __half2float(zu.h[g * 4 + i]);                              \
    {                                                                          \
      const uint4* p = (const uint4*)(((unsigned)wn < WW) ? zcur : zbias);     \
      zu.q[0] = p[0];                                                          \
      zu.q[1] = p[1];                                                          \
      wn++;                                                                    \
      zcur += 512;                                                             \
    }                                                                          \
    v4f acc0[4], acc1[4];                                                      \
    _Pragma("unroll") for (int g = 0; g < 4; g++) {                            \
      acc0[g] = (v4f){0.f, 0.f, 0.f, 0.f};                                     \
      acc1[g] = zi[g];                                                         \
    }                                                                          \
    _Pragma("unroll") for (int kt = 0; kt < 4; kt++) {                         \
      _Pragma("unroll") for (int g = 0; g < 4; g++)                            \
          acc0[g] = __builtin_amdgcn_mfma_f32_16x16x32_f16(                    \
              wfrag[g][kt], bfr[kt], acc0[g], 0, 0, 0);                        \
    }                                                                          \
    _Pragma("unroll") for (int kt = 0; kt < 4; kt++) {                         \
      v8h bf1 = *(const v8h*)&h_lds[RB][((rl + 1) * 2 + bl) * HROW + kt * 32 + \
                                        quad * 8];                             \
      _Pragma("unroll") for (int g = 0; g < 4; g++)                            \
          acc1[g] = __builtin_amdgcn_mfma_f32_16x16x32_f16(                    \
              wfrag[g][4 + kt], bf1, acc1[g], 0, 0, 0);                        \
    }                                                                          \
    unsigned long long pend = 0ull;                                            \
    if (is_cons)                                                               \
      pend = __hip_atomic_load(ca, __ATOMIC_RELAXED,                           \
                               __HIP_MEMORY_SCOPE_AGENT);                      \
    const int w = (T)-r;                                                       \
    const bool inband = ((unsigned)w < WW);                                    \
    float hv[4];                                                               \
    _Pragma("unroll") for (int rg2 = 0; rg2 < 4; rg2++) {                      \
      float z0 = acc0[0][rg2] + acc1[0][rg2];                                  \
      float z1 = acc0[1][rg2] + acc1[1][rg2];                                  \
      float z2 = acc0[2][rg2] + acc1[2][rg2];                                  \
      float z3 = acc0[3][rg2] + acc1[3][rg2];                                  \
      float iv = fsig(z0);                                                     \
      float fv = fsig(z1);                                                     \
      float ov = fsig(z2);                                                     \
      float gv = ftanh_(z3);                                                   \
      c[rg2] = fv * c[rg2] + iv * gv;                                          \
      hv[rg2] = ov * ftanh_(c[rg2]);                                           \
    }                                                                          \
    __half2 plo = __floats2half2_rn(hv[0], hv[1]);                             \
    __half2 phi = __floats2half2_rn(hv[2], hv[3]);                             \
    {                                                                          \
      uint2 pk;                                                                \
      pk.x = *(unsigned*)&plo;                                                 \
      pk.y = *(unsigned*)&phi;                                                 \
      *(uint2*)&h_lds[(RB) ^ 1][((rl + 1) * 2 + bl) * HROW + uq0] = pk;        \
    }                                                                          \
    if (rgr < 7 && l15 >= 14) {                                                \
      unsigned long long pk =                                                  \
          ((unsigned long long)*(unsigned*)&phi << 32) | *(unsigned*)&plo;     \
      __hip_atomic_store(pa, pk, __ATOMIC_RELAXED, __HIP_MEMORY_SCOPE_AGENT);  \
    }                                                                          \
    pa += 2048;                                                                \
    _Pragma("unroll") for (int rg2 = 0; rg2 < 4; rg2++) {                      \
      outb[rg2].x = outb[rg2].y;                                               \
      outb[rg2].y = outb[rg2].z;                                               \
      outb[rg2].z = outb[rg2].w;                                               \
      outb[rg2].w = hv[rg2];                                                   \
    }                                                                          \
    if (inband && (w & 3) == 3) {                                              \
      *(float4*)op0 = outb[0];                                                 \
      *(float4*)op1 = outb[1];                                                 \
      *(float4*)op2 = outb[2];                                                 \
      *(float4*)op3 = outb[3];                                                 \
      op0 += 4; op1 += 4; op2 += 4; op3 += 4;                                  \
    }                                                                          \
    if (is_cons) {                                                             \
      while (__ballot(pend == SENT64) != 0ull) {                               \
        __builtin_amdgcn_s_sleep(1);                                           \
        pend = __hip_atomic_load(ca, __ATOMIC_RELAXED,                         \
                                 __HIP_MEMORY_SCOPE_AGENT);                    \
      }                                                                        \
      *(unsigned long long*)&h_lds[(RB) ^ 1][(0 * 2 + ebl) * HROW + eu] =      \
          pend;                                                                \
    }                                                                          \
    ca += 2048;                                                                \
    STEP_BARRIER();                                                            \
  } while (0)

__global__ __launch_bounds__(512, 1) void lstm_mfma32(
    const __half* __restrict__ zph, const _Float16* __restrict__ wp,
    unsigned long long* __restrict__ hx, float* __restrict__ out) {
  const int blk = blockIdx.x;
  const int rgr = blk >> 2;
  const int bg = blk & 3;
  const int R0 = rgr * 8;
  const int tid = threadIdx.x;
  const int wv = tid >> 6;
  const int L = tid & 63;
  const int quad = L >> 4;
  const int l15 = L & 15;
  const int rl = l15 >> 1;
  const int bl = l15 & 1;
  const int b = bg * 2 + bl;
  const int r = R0 + rl;
  const int uq0 = 16 * wv + quad * 4;
  const int zoff = (4 * wv + quad) * 16;

  __shared__ _Float16 h_lds[2][9 * 2 * HROW];
  for (int i = tid; i < (2 * 9 * 2 * HROW) / 2; i += 512)
    ((unsigned*)h_lds)[i] = 0u;

  v8h wfrag[4][8];
  {
    const v8h* wp8 = (const v8h*)wp;
#pragma unroll
    for (int g = 0; g < 4; g++)
#pragma unroll
      for (int kt = 0; kt < 8; kt++)
        wfrag[g][kt] = wp8[((size_t)((8 * g + wv) * 8 + kt)) * 64 + L];
  }

  float c[4] = {0.f, 0.f, 0.f, 0.f};
  float4 outb[4];
#pragma unroll
  for (int i = 0; i < 4; i++) outb[i] = make_float4(0.f, 0.f, 0.f, 0.f);

  const int ebl = L >> 5;
  const int eu = (L & 31) * 4;
  const int exp_idx = bl * 32 + 4 * wv + quad;

  const bool is_cons = (wv == 0) && (rgr > 0);

  const __half* zpp = zph + ((size_t)b * HH + r) * WW * 512 + zoff;
  const __half* zbias = zph + (size_t)BB * HH * WW * 512 + zoff;
  const unsigned long long* ca =
      hx + (((size_t)(rgr > 0 ? rgr - 1 : 0) * 4 + bg) * 64 + L);
  unsigned long long* pa = hx + (((size_t)rgr * 4 + bg) * 64 + exp_idx);
  float* op0 = out + (((size_t)b * HID + uq0 + 0) * HH + r) * WW;
  float* op1 = out + (((size_t)b * HID + uq0 + 1) * HH + r) * WW;
  float* op2 = out + (((size_t)b * HID + uq0 + 2) * HH + r) * WW;
  float* op3 = out + (((size_t)b * HID + uq0 + 3) * HH + r) * WW;

  union ZU {
    uint4 q[2];
    __half h[16];
  } zu;
  {
    const uint4* p0 = (const uint4*)((r == 0) ? zpp : zbias);
    zu.q[0] = p0[0];
    zu.q[1] = p0[1];
  }
  int wn = 1 - r;
  const __half* zcur = zpp + (ptrdiff_t)wn * 512;

  __syncthreads();

  for (int t = 0; t < TT - 1; t += 2) {
    STEP_BODY(t, 0);
    STEP_BODY(t + 1, 1);
  }
  STEP_BODY(TT - 1, 0);
}

// ================= round-1 fallback path (proven correct) =================
__global__ __launch_bounds__(256) void transpose_x(const float* __restrict__ x,
                                                   float* __restrict__ xT) {
  int b = blockIdx.x >> 6;
  int r = blockIdx.x & 63;
  __shared__ float tile[32][65];
  for (int cc = 0; cc < 4; cc++) {
    int cl = threadIdx.x >> 6;
    int w = threadIdx.x & 63;
#pragma unroll
    for (int k = 0; k < 8; k++) {
      int c_loc = k * 4 + cl;
      int c = cc * 32 + c_loc;
      tile[c_loc][w] = x[(((size_t)b * 128 + c) * HH + r) * WW + w];
    }
    __syncthreads();
    int cs = threadIdx.x & 31;
    int wp = threadIdx.x >> 5;
#pragma unroll
    for (int k = 0; k < 8; k++) {
      int w2 = wp * 8 + k;
      xT[(((size_t)b * HH + r) * WW + w2) * 128 + cc * 32 + cs] = tile[cs][w2];
    }
    __syncthreads();
  }
}

__global__ __launch_bounds__(256) void step_kernel(
    const float* __restrict__ x, const float* __restrict__ xT, int use_xT,
    const float* __restrict__ w_is, const float* __restrict__ b_is,
    const float* __restrict__ w_ss, const float* __restrict__ b_ss,
    const float* __restrict__ h_prev, float* __restrict__ h_next,
    float* __restrict__ c_state, float* __restrict__ out, int t) {
  const int rg = blockIdx.x;
  const int q = blockIdx.y;
  const int r0 = rg * 2;
  const int tid = threadIdx.x;
  const int o_loc = tid & 63;
  const int k4 = tid >> 6;
  const int g_ = o_loc >> 4;
  const int u_ = o_loc & 15;
  const int O = g_ * 128 + q * 16 + u_;
  const int i0 = k4 * 32;

  __shared__ __align__(16) float h_in[3][BB][HID];
  __shared__ float zred[16][4][65];

  for (int idx = tid; idx < 3 * BB * HID; idx += 256) {
    int row_sel = idx >> 10;
    int rem = idx & 1023;
    int b = rem >> 7;
    int u = rem & 127;
    int rr = r0 - 1 + row_sel;
    h_in[row_sel][b][u] = (rr >= 0) ? h_prev[((size_t)b * HH + rr) * HID + u] : 0.0f;
  }

  float wr0[32], wr1[32], wz[32];
  {
    const float4* wss4 = (const float4*)(w_ss + ((size_t)O * 128 + i0) * 2);
#pragma unroll
    for (int j = 0; j < 16; j++) {
      float4 v = wss4[j];
      wr0[2 * j] = v.x;
      wr1[2 * j] = v.y;
      wr0[2 * j + 1] = v.z;
      wr1[2 * j + 1] = v.w;
    }
    const float4* wis4 = (const float4*)(w_is + (size_t)O * 128 + i0);
#pragma unroll
    for (int j = 0; j < 8; j++) {
      float4 v = wis4[j];
      wz[4 * j] = v.x;
      wz[4 * j + 1] = v.y;
      wz[4 * j + 2] = v.z;
      wz[4 * j + 3] = v.w;
    }
  }

  __syncthreads();

  float acc[2][BB];
#pragma unroll
  for (int rl = 0; rl < 2; rl++)
#pragma unroll
    for (int b = 0; b < BB; b++) acc[rl][b] = 0.0f;

#pragma unroll
  for (int jb = 0; jb < 8; jb++) {
    int ib = i0 + jb * 4;
#pragma unroll
    for (int b = 0; b < BB; b++) {
      const float4 hm4 = *(const float4*)&h_in[0][b][ib];
      const float4 hc4 = *(const float4*)&h_in[1][b][ib];
      const float4 hp4 = *(const float4*)&h_in[2][b][ib];
      const float* hm = (const float*)&hm4;
      const float* hc = (const float*)&hc4;
      const float* hq = (const float*)&hp4;
#pragma unroll
      for (int jj = 0; jj < 4; jj++) {
        float w0v = wr0[jb * 4 + jj];
        float w1v = wr1[jb * 4 + jj];
        acc[0][b] += w0v * hm[jj] + w1v * hc[jj];
        acc[1][b] += w0v * hc[jj] + w1v * hq[jj];
      }
    }
  }

#pragma unroll
  for (int rl = 0; rl < 2; rl++) {
    int rr = r0 + rl;
    int wcol = t - rr;
    if (wcol >= 0 && wcol < WW) {
      if (use_xT) {
        for (int b = 0; b < BB; b++) {
          const float4* xp =
              (const float4*)(xT + (((size_t)b * HH + rr) * WW + wcol) * 128 + i0);
#pragma unroll
          for (int j = 0; j < 8; j++) {
            float4 v = xp[j];
            acc[rl][b] += wz[4 * j] * v.x + wz[4 * j + 1] * v.y +
                          wz[4 * j + 2] * v.z + wz[4 * j + 3] * v.w;
          }
        }
      } else {
        for (int b = 0; b < BB; b++) {
          const float* xb = x + (((size_t)b * 128 + i0) * HH + rr) * WW + wcol;
#pragma unroll
          for (int j = 0; j < 32; j++) {
            acc[rl][b] += wz[j] * xb[(size_t)j * HH * WW];
          }
        }
      }
    }
  }

#pragma unroll
  for (int rl = 0; rl < 2; rl++)
#pragma unroll
    for (int b = 0; b < BB; b++) zred[rl * 8 + b][k4][o_loc] = acc[rl][b];
  __syncthreads();

  {
    int u = tid >> 4;
    int cell = tid & 15;
    int rl = cell >> 3;
    int b = cell & 7;
    int rr = r0 + rl;
    float z[4];
#pragma unroll
    for (int gg = 0; gg < 4; gg++) {
      int ol = gg * 16 + u;
      float s = zred[cell][0][ol] + zred[cell][1][ol] + zred[cell][2][ol] +
                zred[cell][3][ol];
      int Og = gg * 128 + q * 16 + u;
      z[gg] = s + b_is[Og] + b_ss[Og];
    }
    float iv = 1.0f / (1.0f + expf(-z[0]));
    float fv = 1.0f / (1.0f + expf(-z[1]));
    float ov = 1.0f / (1.0f + expf(-z[2]));
    float gv = tanhf(z[3]);
    int U = q * 16 + u;
    size_t sidx = ((size_t)b * HH + rr) * HID + U;
    float cv = c_state[sidx];
    float cn = fv * cv + iv * gv;
    c_state[sidx] = cn;
    float hn = ov * tanhf(cn);
    h_next[sidx] = hn;
    int wcol = t - rr;
    if (wcol >= 0 && wcol < WW) {
      out[(((size_t)b * HID + U) * HH + rr) * WW + wcol] = hn;
    }
  }
}

extern "C" void kernel_launch(void* const* d_in, const int* in_sizes, int n_in,
                              void* d_out, int out_size, void* d_ws,
                              size_t ws_size, hipStream_t stream) {
  const float* x = (const float*)d_in[0];
  const float* w_is = (const float*)d_in[1];
  const float* b_is = (const float*)d_in[2];
  const float* w_ss = (const float*)d_in[3];
  const float* b_ss = (const float*)d_in[4];
  float* outp = (float*)d_out;

  const size_t zph_bytes = ((size_t)BB * HH * WW * 512 + 512) * 2;
  const size_t wp_bytes = (size_t)512 * 256 * 2;
  const size_t hx_bytes = (size_t)TT * 8 * 4 * 64 * 8;
  const size_t hp_bytes = (size_t)(TT + 1) * 64 * 256 * 8;  // 16.8 MB
  const size_t need32 = zph_bytes + wp_bytes + hx_bytes;
  const size_t need64 = need32 + hp_bytes;

  char* ws = (char*)d_ws;
  if (ws_size >= need64) {
    __half* zph = (__half*)ws;
    _Float16* wpp = (_Float16*)(ws + zph_bytes);
    unsigned long long* hx = (unsigned long long*)(ws + zph_bytes + wp_bytes);
    unsigned long long* hp = (unsigned long long*)(ws + need32);

    prep_zpre<<<dim3(NPREP64 + 512), 256, 0, stream>>>(
        x, w_is, b_is, b_ss, w_ss, wpp, zph, hx, hp, NPREP64);
    lstm_mfma64<<<dim3(64), 256, 0, stream>>>(zph, wpp, hx, hp, outp);
  } else if (ws_size >= need32) {
    __half* zph = (__half*)ws;
    _Float16* wpp = (_Float16*)(ws + zph_bytes);
    unsigned long long* hx = (unsigned long long*)(ws + zph_bytes + wp_bytes);

    prep_zpre<<<dim3(NPREP32 + 512), 256, 0, stream>>>(
        x, w_is, b_is, b_ss, w_ss, wpp, zph, hx, hx, NPREP32);
    lstm_mfma32<<<dim3(32), 512, 0, stream>>>(zph, wpp, hx, outp);
  } else {
    // -------- round-1 fallback --------
    const size_t xT_elems = (size_t)BB * HH * WW * 128;
    const size_t st_elems = (size_t)BB * HH * HID;
    const size_t need_xT = (xT_elems + 3 * st_elems) * sizeof(float);
    float* wsf = (float*)d_ws;
    float* xT = nullptr;
    float* st;
    int use_xT = 0;
    if (ws_size >= need_xT) {
      use_xT = 1;
      xT = wsf;
      st = wsf + xT_elems;
    } else {
      st = wsf;
    }
    float* h0 = st;
    float* h1 = st + st_elems;
    float* cb = st + 2 * st_elems;
    hipMemsetAsync(st, 0, 3 * st_elems * sizeof(float), stream);
    if (use_xT) transpose_x<<<dim3(BB * HH), 256, 0, stream>>>(x, xT);
    for (int t = 0; t < TT; t++) {
      float* hp2 = (t & 1) ? h1 : h0;
      float* hn = (t & 1) ? h0 : h1;
      step_kernel<<<dim3(32, 8), 256, 0, stream>>>(x, xT, use_xT, w_is, b_is,
                                                   w_ss, b_ss, hp2, hn, cb,
                                                   outp, t);
    }
  }
}

// Round 7
// 435.383 us; speedup vs baseline: 1.7515x; 1.7515x over previous
//
#include <hip/hip_runtime.h>
#include <hip/hip_fp16.h>
#include <math.h>

// DiagonalLSTM: B=8, Cin=HID=128, H=64, W=64, K=2, T = 2W-1 = 127 steps.
//
// Round 21 design (revert R20's M-split; R19 structure + 4-wave g-doubling):
//   - R20 post-mortem: symmetric per-step partner exchange through global
//     memory put a store->L2->load round trip + spin inside every step for
//     every thread (WRITE_SIZE 18->95MB) -> 3.5x regression. Reverted.
//   - R19 per-step model: LDS read volume dominates (8 waves x 8
//     ds_read_b128 = 64KB/step/CU ~ 770cy at measured 85B/cy; MFMA ~310,
//     trans ~320). All 8 waves read the SAME 64 B-frag addresses.
//   - Fix: 32 blocks x 256 thr (4 waves), each wave owns TWO m-tiles
//     (wfragA: units 16wv.., wfragB: units 64+16wv.. per gate) and reads
//     the shared 8 B-frags ONCE -> LDS reads halve (~385cy saved/step).
//     MFMA and trans per SIMD unchanged. 1 wave/SIMD, reg budget 512
//     (A-frags AGPR-eligible on gfx950 unified file).
//   - everything else is proven R19: merged prep+zpre, z via MFMA
//     C-operand (both tiles), lazy mid-step hx boundary load, LDS-only
//     step barrier, 2x-unrolled t-loop, bias folded into zph, incremental
//     pointers, reg-buffered out stores, clamp-free fsig/ftanh.

#define HID 128
#define BB 8
#define HH 64
#define WW 64
#define TT 127

// prep item counts: 131072 (wp frags) + 512 (zph bias) + 130048 (hx fill)
//                 = 261632 = 1022 * 256 exactly
#define NPREP 1022

#define HROW 136  // padded LDS row stride in halfs

typedef _Float16 v8h __attribute__((ext_vector_type(8)));
typedef float v4f __attribute__((ext_vector_type(4)));

#define SENT64 0xFFFFFFFFFFFFFFFFULL  // 4x f16 -NaN (0xFF fill pattern)

__device__ __forceinline__ float fsig(float x) {
  float e = __builtin_amdgcn_exp2f(x * -1.44269504f);
  return __builtin_amdgcn_rcpf(1.f + e);
}
__device__ __forceinline__ float ftanh_(float x) {
  float e = __builtin_amdgcn_exp2f(x * 2.88539009f);
  return __builtin_fmaf(-2.f, __builtin_amdgcn_rcpf(1.f + e), 1.f);
}

// ---- merged prep + zpre kernel (R18/R19 verbatim) ----
__global__ __launch_bounds__(256) void prep_zpre(
    const float* __restrict__ x, const float* __restrict__ w_is,
    const float* __restrict__ b_is, const float* __restrict__ b_ss,
    const float* __restrict__ w_ss, _Float16* __restrict__ wp,
    __half* __restrict__ zph, unsigned long long* __restrict__ hx) {
  const int bid = blockIdx.x;
  const int tid = threadIdx.x;

  __shared__ _Float16 xt[64][136];  // zpre half only

  if (bid < NPREP) {
    int idx = bid * 256 + tid;
    if (idx < 131072) {
      // w_ss -> Wcat(512x256) A-frags: wp[(((mt*8+kt)*64+L)*8+j)]
      int j = idx & 7;
      int L = (idx >> 3) & 63;
      int kt = (idx >> 9) & 7;
      int mt = idx >> 12;
      int O = mt * 16 + (L & 15);
      int k = kt * 32 + ((L >> 4) & 3) * 8 + j;
      float v = (k < 128) ? w_ss[(size_t)O * 256 + k * 2]
                          : w_ss[(size_t)O * 256 + (k - 128) * 2 + 1];
      wp[idx] = (_Float16)v;
    } else if (idx < 131584) {
      // zph bias slot: layout idx2 = (u>>2)*16 + g*4 + (u&3)
      int idx2 = idx - 131072;  // 0..511
      int g = (idx2 >> 2) & 3;
      int u = (idx2 >> 4) * 4 + (idx2 & 3);
      int O = g * 128 + u;
      zph[(size_t)BB * HH * WW * 512 + idx2] = __float2half(b_is[O] + b_ss[O]);
    } else {
      // hx sentinel fill: 260096 u64 as 130048 x 16B
      int j = idx - 131584;
      uint4 s;
      s.x = 0xFFFFFFFFu; s.y = 0xFFFFFFFFu;
      s.z = 0xFFFFFFFFu; s.w = 0xFFFFFFFFu;
      ((uint4*)hx)[j] = s;
    }
    return;
  }

  // ---------------- zpre half ----------------
  const int zb = bid - NPREP;  // 0..511
  const int b = zb >> 6;
  const int r = zb & 63;
  const int wv = tid >> 6;
  const int L = tid & 63;
  const int quad = L >> 4;
  const int l15 = L & 15;

  {
    const int cw = tid >> 4;
    const int w4 = (tid & 15) * 4;
#pragma unroll
    for (int p = 0; p < 8; p++) {
      int c = p * 16 + cw;
      float4 v = *(const float4*)&x[(((size_t)b * 128 + c) * HH + r) * WW + w4];
      xt[w4 + 0][c] = (_Float16)v.x;
      xt[w4 + 1][c] = (_Float16)v.y;
      xt[w4 + 2][c] = (_Float16)v.z;
      xt[w4 + 3][c] = (_Float16)v.w;
    }
  }

  v8h wfr[8][4];
  float4 bv[8];
#pragma unroll
  for (int m = 0; m < 8; m++) {
    const int mt = 8 * wv + m;
    const int O = mt * 16 + l15;
#pragma unroll
    for (int kt = 0; kt < 4; kt++) {
      const float* p = w_is + (size_t)O * 128 + kt * 32 + quad * 8;
      float4 a = *(const float4*)p;
      float4 b2 = *(const float4*)(p + 4);
      v8h f;
      f[0] = (_Float16)a.x;  f[1] = (_Float16)a.y;
      f[2] = (_Float16)a.z;  f[3] = (_Float16)a.w;
      f[4] = (_Float16)b2.x; f[5] = (_Float16)b2.y;
      f[6] = (_Float16)b2.z; f[7] = (_Float16)b2.w;
      wfr[m][kt] = f;
    }
    const int O4 = mt * 16 + quad * 4;
    float4 bi = *(const float4*)&b_is[O4];
    float4 bs4 = *(const float4*)&b_ss[O4];
    bv[m] = make_float4(bi.x + bs4.x, bi.y + bs4.y, bi.z + bs4.z, bi.w + bs4.w);
  }

  __syncthreads();

#pragma unroll
  for (int nt = 0; nt < 4; nt++) {
    v8h bf[4];
#pragma unroll
    for (int kt = 0; kt < 4; kt++)
      bf[kt] = *(const v8h*)&xt[nt * 16 + l15][kt * 32 + quad * 8];
    const size_t pos = ((size_t)b * HH + r) * WW + nt * 16 + l15;
#pragma unroll
    for (int m = 0; m < 8; m++) {
      v4f acc = (v4f){0.f, 0.f, 0.f, 0.f};
#pragma unroll
      for (int kt = 0; kt < 4; kt++)
        acc = __builtin_amdgcn_mfma_f32_16x16x32_f16(wfr[m][kt], bf[kt], acc,
                                                     0, 0, 0);
      __half2 lo = __floats2half2_rn(acc[0] + bv[m].x, acc[1] + bv[m].y);
      __half2 hi = __floats2half2_rn(acc[2] + bv[m].z, acc[3] + bv[m].w);
      uint2 pk;
      pk.x = *(unsigned*)&lo;
      pk.y = *(unsigned*)&hi;
      *(uint2*)&zph[pos * 512 + (m * 4 + quad) * 16 + wv * 4] = pk;
    }
  }
}

// Step barrier: LDS-visibility only (no vmcnt drain; see R15 notes).
#define STEP_BARRIER()                                   \
  do {                                                   \
    asm volatile("s_waitcnt lgkmcnt(0)" ::: "memory");   \
    __builtin_amdgcn_s_barrier();                        \
    asm volatile("" ::: "memory");                       \
  } while (0)

#define HPLD(p) __hip_atomic_load((p), __ATOMIC_RELAXED, __HIP_MEMORY_SCOPE_AGENT)

// ---------------- persistent 4-wave MFMA recurrent kernel -------------
// One step, compile-time read buffer RB (write = RB^1).
// Wave wv owns m-tiles A (units 16wv+..) and B (units 64+16wv+..) for all
// 4 gates; B-frags are read once and feed both tiles' MFMAs.
#define STEP4W(T, RB)                                                          \
  do {                                                                         \
    /* shared B-frags: chain-0 (slot rl) + chain-1 (slot rl+1), 8 reads */     \
    v8h bfr[4], bf1[4];                                                        \
    _Pragma("unroll") for (int kt = 0; kt < 4; kt++)                           \
        bfr[kt] = *(const v8h*)&h_lds[RB][(rl * 2 + bl) * HROW + kt * 32 +     \
                                          quad * 8];                           \
    _Pragma("unroll") for (int kt = 0; kt < 4; kt++)                           \
        bf1[kt] = *(const v8h*)&h_lds[RB][((rl + 1) * 2 + bl) * HROW +         \
                                          kt * 32 + quad * 8];                 \
    /* convert z for both tiles (chain-1 C-operand init) */                    \
    v4f ziA[4], ziB[4];                                                        \
    _Pragma("unroll") for (int g = 0; g < 4; g++)                              \
        _Pragma("unroll") for (int i = 0; i < 4; i++) {                        \
      ziA[g][i] = __half2float(zuA.h[g * 4 + i]);                              \
      ziB[g][i] = __half2float(zuB.h[g * 4 + i]);                              \
    }                                                                          \
    /* zp prefetch for T+1: A at +0, B at +256 halfs (=+32 uint4) */           \
    {                                                                          \
      const uint4* p = (const uint4*)(((unsigned)wn < WW) ? zcur : zbias);     \
      zuA.q[0] = p[0];                                                         \
      zuA.q[1] = p[1];                                                         \
      zuB.q[0] = p[32];                                                        \
      zuB.q[1] = p[33];                                                        \
      wn++;                                                                    \
      zcur += 512;                                                             \
    }                                                                          \
    /* MFMA: 2 chains x 2 tiles, shared B-frags */                             \
    v4f a0[4], a1[4], b0[4], b1[4];                                            \
    _Pragma("unroll") for (int g = 0; g < 4; g++) {                            \
      a0[g] = (v4f){0.f, 0.f, 0.f, 0.f};                                       \
      b0[g] = (v4f){0.f, 0.f, 0.f, 0.f};                                       \
      a1[g] = ziA[g];                                                          \
      b1[g] = ziB[g];                                                          \
    }                                                                          \
    _Pragma("unroll") for (int kt = 0; kt < 4; kt++) {                         \
      _Pragma("unroll") for (int g = 0; g < 4; g++)                            \
          a0[g] = __builtin_amdgcn_mfma_f32_16x16x32_f16(wfA[g][kt], bfr[kt],  \
                                                         a0[g], 0, 0, 0);      \
      _Pragma("unroll") for (int g = 0; g < 4; g++)                            \
          b0[g] = __builtin_amdgcn_mfma_f32_16x16x32_f16(wfB[g][kt], bfr[kt],  \
                                                         b0[g], 0, 0, 0);      \
    }                                                                          \
    _Pragma("unroll") for (int kt = 0; kt < 4; kt++) {                         \
      _Pragma("unroll") for (int g = 0; g < 4; g++)                            \
          a1[g] = __builtin_amdgcn_mfma_f32_16x16x32_f16(wfA[g][4 + kt],       \
                                                         bf1[kt], a1[g], 0, 0, \
                                                         0);                   \
      _Pragma("unroll") for (int g = 0; g < 4; g++)                            \
          b1[g] = __builtin_amdgcn_mfma_f32_16x16x32_f16(wfB[g][4 + kt],       \
                                                         bf1[kt], b1[g], 0, 0, \
                                                         0);                   \
    }                                                                          \
    /* mid-step hx boundary load (R19 lazy) */                                 \
    unsigned long long pend = 0ull;                                            \
    if (is_cons) pend = HPLD(ca);                                              \
    /* gates, both tiles */                                                    \
    const int w = (T)-r;                                                       \
    const bool inband = ((unsigned)w < WW);                                    \
    float hvA[4], hvB[4];                                                      \
    _Pragma("unroll") for (int rg2 = 0; rg2 < 4; rg2++) {                      \
      float z0 = a0[0][rg2] + a1[0][rg2];                                      \
      float z1 = a0[1][rg2] + a1[1][rg2];                                      \
      float z2 = a0[2][rg2] + a1[2][rg2];                                      \
      float z3 = a0[3][rg2] + a1[3][rg2];                                      \
      float iv = fsig(z0);                                                     \
      float fv = fsig(z1);                                                     \
      float ov = fsig(z2);                                                     \
      float gv = ftanh_(z3);                                                   \
      cA[rg2] = fv * cA[rg2] + iv * gv;                                        \
      hvA[rg2] = ov * ftanh_(cA[rg2]);                                         \
    }                                                                          \
    _Pragma("unroll") for (int rg2 = 0; rg2 < 4; rg2++) {                      \
      float z0 = b0[0][rg2] + b1[0][rg2];                                      \
      float z1 = b0[1][rg2] + b1[1][rg2];                                      \
      float z2 = b0[2][rg2] + b1[2][rg2];                                      \
      float z3 = b0[3][rg2] + b1[3][rg2];                                      \
      float iv = fsig(z0);                                                     \
      float fv = fsig(z1);                                                     \
      float ov = fsig(z2);                                                     \
      float gv = ftanh_(z3);                                                   \
      cB[rg2] = fv * cB[rg2] + iv * gv;                                        \
      hvB[rg2] = ov * ftanh_(cB[rg2]);                                         \
    }                                                                          \
    /* pack + LDS write (both tiles) */                                        \
    __half2 ploA = __floats2half2_rn(hvA[0], hvA[1]);                          \
    __half2 phiA = __floats2half2_rn(hvA[2], hvA[3]);                          \
    __half2 ploB = __floats2half2_rn(hvB[0], hvB[1]);                          \
    __half2 phiB = __floats2half2_rn(hvB[2], hvB[3]);                          \
    {                                                                          \
      uint2 pk;                                                                \
      pk.x = *(unsigned*)&ploA;                                                \
      pk.y = *(unsigned*)&phiA;                                                \
      *(uint2*)&h_lds[(RB) ^ 1][((rl + 1) * 2 + bl) * HROW + uq0] = pk;        \
      pk.x = *(unsigned*)&ploB;                                                \
      pk.y = *(unsigned*)&phiB;                                                \
      *(uint2*)&h_lds[(RB) ^ 1][((rl + 1) * 2 + bl) * HROW + uq0 + 64] = pk;   \
    }                                                                          \
    /* export h(T)[R0+7], both tiles: fire-and-forget (data == flag) */        \
    if (rgr < 7 && l15 >= 14) {                                                \
      unsigned long long pkA =                                                 \
          ((unsigned long long)*(unsigned*)&phiA << 32) | *(unsigned*)&ploA;   \
      unsigned long long pkB =                                                 \
          ((unsigned long long)*(unsigned*)&phiB << 32) | *(unsigned*)&ploB;   \
      __hip_atomic_store(pa_hx, pkA, __ATOMIC_RELAXED,                         \
                         __HIP_MEMORY_SCOPE_AGENT);                            \
      __hip_atomic_store(pa_hx + 16, pkB, __ATOMIC_RELAXED,                    \
                         __HIP_MEMORY_SCOPE_AGENT);                            \
    }                                                                          \
    pa_hx += 2048;                                                             \
    /* out shift-window; 16B flush every 4 steps per cell, both tiles */       \
    _Pragma("unroll") for (int rg2 = 0; rg2 < 4; rg2++) {                      \
      outbA[rg2].x = outbA[rg2].y;                                             \
      outbA[rg2].y = outbA[rg2].z;                                             \
      outbA[rg2].z = outbA[rg2].w;                                             \
      outbA[rg2].w = hvA[rg2];                                                 \
      outbB[rg2].x = outbB[rg2].y;                                             \
      outbB[rg2].y = outbB[rg2].z;                                             \
      outbB[rg2].z = outbB[rg2].w;                                             \
      outbB[rg2].w = hvB[rg2];                                                 \
    }                                                                          \
    if (inband && (w & 3) == 3) {                                              \
      *(float4*)opA0 = outbA[0];                                               \
      *(float4*)opA1 = outbA[1];                                               \
      *(float4*)opA2 = outbA[2];                                               \
      *(float4*)opA3 = outbA[3];                                               \
      *(float4*)opB0 = outbB[0];                                               \
      *(float4*)opB1 = outbB[1];                                               \
      *(float4*)opB2 = outbB[2];                                               \
      *(float4*)opB3 = outbB[3];                                               \
      opA0 += 4; opA1 += 4; opA2 += 4; opA3 += 4;                              \
      opB0 += 4; opB1 += 4; opB2 += 4; opB3 += 4;                              \
    }                                                                          \
    /* validate pend (hx[T] = h(T)[R0-1]) -> wb slot 0 */                      \
    if (is_cons) {                                                             \
      while (__ballot(pend == SENT64) != 0ull) {                               \
        __builtin_amdgcn_s_sleep(1);                                           \
        pend = HPLD(ca);                                                       \
      }                                                                        \
      *(unsigned long long*)&h_lds[(RB) ^ 1][(0 * 2 + ebl) * HROW + eu] =      \
          pend;                                                                \
    }                                                                          \
    ca += 2048;                                                                \
    STEP_BARRIER();                                                            \
  } while (0)

__global__ __launch_bounds__(256, 1) void lstm_mfma4w(
    const __half* __restrict__ zph, const _Float16* __restrict__ wp,
    unsigned long long* __restrict__ hx,  // [TT][8][4][64], sentinel-filled
    float* __restrict__ out) {
  const int blk = blockIdx.x;  // 0..31
  const int rgr = blk >> 2;    // row group 0..7 (rows 8*rgr .. +7)
  const int bg = blk & 3;      // batch group 0..3 (b = 2*bg, 2*bg+1)
  const int R0 = rgr * 8;
  const int tid = threadIdx.x;
  const int wv = tid >> 6;  // wave 0..3
  const int L = tid & 63;
  const int quad = L >> 4;
  const int l15 = L & 15;
  const int rl = l15 >> 1;  // cell row-local 0..7
  const int bl = l15 & 1;   // cell batch-local 0..1
  const int b = bg * 2 + bl;
  const int r = R0 + rl;
  const int uq0 = 16 * wv + quad * 4;  // tile-A unit base; tile-B = +64
  const int ugA = 4 * wv + quad;       // unit group 0..15 (tile B: +16)
  const int zoffA = ugA * 16;          // zp contiguous 16-half group (A)

  // double-buffered: slot s holds row R0-1+s (s=0..8), per b-local
  __shared__ _Float16 h_lds[2][9 * 2 * HROW];
  for (int i = tid; i < (2 * 9 * 2 * HROW) / 2; i += 256)
    ((unsigned*)h_lds)[i] = 0u;

  // ---- weights as A-fragments, loaded once (2 m-tiles per wave) ----
  v8h wfA[4][8], wfB[4][8];
  {
    const v8h* wp8 = (const v8h*)wp;
#pragma unroll
    for (int g = 0; g < 4; g++)
#pragma unroll
      for (int kt = 0; kt < 8; kt++) {
        wfA[g][kt] = wp8[((size_t)((8 * g + wv) * 8 + kt)) * 64 + L];
        wfB[g][kt] = wp8[((size_t)((8 * g + wv + 4) * 8 + kt)) * 64 + L];
      }
  }

  float cA[4] = {0.f, 0.f, 0.f, 0.f};
  float cB[4] = {0.f, 0.f, 0.f, 0.f};
  float4 outbA[4], outbB[4];
#pragma unroll
  for (int i = 0; i < 4; i++) {
    outbA[i] = make_float4(0.f, 0.f, 0.f, 0.f);
    outbB[i] = make_float4(0.f, 0.f, 0.f, 0.f);
  }

  const int ebl = L >> 5;       // boundary consumer: b-local
  const int eu = (L & 31) * 4;  // boundary consumer: unit base
  const int exp_idx = bl * 32 + ugA;  // producer slot A (l15>=14); B = +16

  const bool is_cons = (wv == 0) && (rgr > 0);

  // ---- incremental pointers ----
  const __half* zpp = zph + ((size_t)b * HH + r) * WW * 512 + zoffA;
  const __half* zbias = zph + (size_t)BB * HH * WW * 512 + zoffA;
  const unsigned long long* ca =
      hx + (((size_t)(rgr > 0 ? rgr - 1 : 0) * 4 + bg) * 64 + L);
  unsigned long long* pa_hx = hx + (((size_t)rgr * 4 + bg) * 64 + exp_idx);
  float* opA0 = out + (((size_t)b * HID + uq0 + 0) * HH + r) * WW;
  float* opA1 = out + (((size_t)b * HID + uq0 + 1) * HH + r) * WW;
  float* opA2 = out + (((size_t)b * HID + uq0 + 2) * HH + r) * WW;
  float* opA3 = out + (((size_t)b * HID + uq0 + 3) * HH + r) * WW;
  float* opB0 = out + (((size_t)b * HID + uq0 + 64) * HH + r) * WW;
  float* opB1 = out + (((size_t)b * HID + uq0 + 65) * HH + r) * WW;
  float* opB2 = out + (((size_t)b * HID + uq0 + 66) * HH + r) * WW;
  float* opB3 = out + (((size_t)b * HID + uq0 + 67) * HH + r) * WW;

  // ---- zp for t=0 (w0 = -r: in-band only for r==0) ----
  union ZU {
    uint4 q[2];
    __half h[16];  // h[g*4 + rg2]
  } zuA, zuB;
  {
    const uint4* p0 = (const uint4*)((r == 0) ? zpp : zbias);
    zuA.q[0] = p0[0];
    zuA.q[1] = p0[1];
    zuB.q[0] = p0[32];
    zuB.q[1] = p0[33];
  }
  int wn = 1 - r;  // next-step w
  const __half* zcur = zpp + (ptrdiff_t)wn * 512;

  __syncthreads();

  // 126 = 63x2 steps with static read-buffer index, then epilogue t=126.
  for (int t = 0; t < TT - 1; t += 2) {
    STEP4W(t, 0);
    STEP4W(t + 1, 1);
  }
  STEP4W(TT - 1, 0);
}

// ================= round-1 fallback path (proven correct) =================
__global__ __launch_bounds__(256) void transpose_x(const float* __restrict__ x,
                                                   float* __restrict__ xT) {
  int b = blockIdx.x >> 6;
  int r = blockIdx.x & 63;
  __shared__ float tile[32][65];
  for (int cc = 0; cc < 4; cc++) {
    int cl = threadIdx.x >> 6;
    int w = threadIdx.x & 63;
#pragma unroll
    for (int k = 0; k < 8; k++) {
      int c_loc = k * 4 + cl;
      int c = cc * 32 + c_loc;
      tile[c_loc][w] = x[(((size_t)b * 128 + c) * HH + r) * WW + w];
    }
    __syncthreads();
    int cs = threadIdx.x & 31;
    int wp = threadIdx.x >> 5;
#pragma unroll
    for (int k = 0; k < 8; k++) {
      int w2 = wp * 8 + k;
      xT[(((size_t)b * HH + r) * WW + w2) * 128 + cc * 32 + cs] = tile[cs][w2];
    }
    __syncthreads();
  }
}

__global__ __launch_bounds__(256) void step_kernel(
    const float* __restrict__ x, const float* __restrict__ xT, int use_xT,
    const float* __restrict__ w_is, const float* __restrict__ b_is,
    const float* __restrict__ w_ss, const float* __restrict__ b_ss,
    const float* __restrict__ h_prev, float* __restrict__ h_next,
    float* __restrict__ c_state, float* __restrict__ out, int t) {
  const int rg = blockIdx.x;
  const int q = blockIdx.y;
  const int r0 = rg * 2;
  const int tid = threadIdx.x;
  const int o_loc = tid & 63;
  const int k4 = tid >> 6;
  const int g_ = o_loc >> 4;
  const int u_ = o_loc & 15;
  const int O = g_ * 128 + q * 16 + u_;
  const int i0 = k4 * 32;

  __shared__ __align__(16) float h_in[3][BB][HID];
  __shared__ float zred[16][4][65];

  for (int idx = tid; idx < 3 * BB * HID; idx += 256) {
    int row_sel = idx >> 10;
    int rem = idx & 1023;
    int b = rem >> 7;
    int u = rem & 127;
    int rr = r0 - 1 + row_sel;
    h_in[row_sel][b][u] = (rr >= 0) ? h_prev[((size_t)b * HH + rr) * HID + u] : 0.0f;
  }

  float wr0[32], wr1[32], wz[32];
  {
    const float4* wss4 = (const float4*)(w_ss + ((size_t)O * 128 + i0) * 2);
#pragma unroll
    for (int j = 0; j < 16; j++) {
      float4 v = wss4[j];
      wr0[2 * j] = v.x;
      wr1[2 * j] = v.y;
      wr0[2 * j + 1] = v.z;
      wr1[2 * j + 1] = v.w;
    }
    const float4* wis4 = (const float4*)(w_is + (size_t)O * 128 + i0);
#pragma unroll
    for (int j = 0; j < 8; j++) {
      float4 v = wis4[j];
      wz[4 * j] = v.x;
      wz[4 * j + 1] = v.y;
      wz[4 * j + 2] = v.z;
      wz[4 * j + 3] = v.w;
    }
  }

  __syncthreads();

  float acc[2][BB];
#pragma unroll
  for (int rl = 0; rl < 2; rl++)
#pragma unroll
    for (int b = 0; b < BB; b++) acc[rl][b] = 0.0f;

#pragma unroll
  for (int jb = 0; jb < 8; jb++) {
    int ib = i0 + jb * 4;
#pragma unroll
    for (int b = 0; b < BB; b++) {
      const float4 hm4 = *(const float4*)&h_in[0][b][ib];
      const float4 hc4 = *(const float4*)&h_in[1][b][ib];
      const float4 hp4 = *(const float4*)&h_in[2][b][ib];
      const float* hm = (const float*)&hm4;
      const float* hc = (const float*)&hc4;
      const float* hq = (const float*)&hp4;
#pragma unroll
      for (int jj = 0; jj < 4; jj++) {
        float w0v = wr0[jb * 4 + jj];
        float w1v = wr1[jb * 4 + jj];
        acc[0][b] += w0v * hm[jj] + w1v * hc[jj];
        acc[1][b] += w0v * hc[jj] + w1v * hq[jj];
      }
    }
  }

#pragma unroll
  for (int rl = 0; rl < 2; rl++) {
    int rr = r0 + rl;
    int wcol = t - rr;
    if (wcol >= 0 && wcol < WW) {
      if (use_xT) {
        for (int b = 0; b < BB; b++) {
          const float4* xp =
              (const float4*)(xT + (((size_t)b * HH + rr) * WW + wcol) * 128 + i0);
#pragma unroll
          for (int j = 0; j < 8; j++) {
            float4 v = xp[j];
            acc[rl][b] += wz[4 * j] * v.x + wz[4 * j + 1] * v.y +
                          wz[4 * j + 2] * v.z + wz[4 * j + 3] * v.w;
          }
        }
      } else {
        for (int b = 0; b < BB; b++) {
          const float* xb = x + (((size_t)b * 128 + i0) * HH + rr) * WW + wcol;
#pragma unroll
          for (int j = 0; j < 32; j++) {
            acc[rl][b] += wz[j] * xb[(size_t)j * HH * WW];
          }
        }
      }
    }
  }

#pragma unroll
  for (int rl = 0; rl < 2; rl++)
#pragma unroll
    for (int b = 0; b < BB; b++) zred[rl * 8 + b][k4][o_loc] = acc[rl][b];
  __syncthreads();

  {
    int u = tid >> 4;
    int cell = tid & 15;
    int rl = cell >> 3;
    int b = cell & 7;
    int rr = r0 + rl;
    float z[4];
#pragma unroll
    for (int gg = 0; gg < 4; gg++) {
      int ol = gg * 16 + u;
      float s = zred[cell][0][ol] + zred[cell][1][ol] + zred[cell][2][ol] +
                zred[cell][3][ol];
      int Og = gg * 128 + q * 16 + u;
      z[gg] = s + b_is[Og] + b_ss[Og];
    }
    float iv = 1.0f / (1.0f + expf(-z[0]));
    float fv = 1.0f / (1.0f + expf(-z[1]));
    float ov = 1.0f / (1.0f + expf(-z[2]));
    float gv = tanhf(z[3]);
    int U = q * 16 + u;
    size_t sidx = ((size_t)b * HH + rr) * HID + U;
    float cv = c_state[sidx];
    float cn = fv * cv + iv * gv;
    c_state[sidx] = cn;
    float hn = ov * tanhf(cn);
    h_next[sidx] = hn;
    int wcol = t - rr;
    if (wcol >= 0 && wcol < WW) {
      out[(((size_t)b * HID + U) * HH + rr) * WW + wcol] = hn;
    }
  }
}

extern "C" void kernel_launch(void* const* d_in, const int* in_sizes, int n_in,
                              void* d_out, int out_size, void* d_ws,
                              size_t ws_size, hipStream_t stream) {
  const float* x = (const float*)d_in[0];
  const float* w_is = (const float*)d_in[1];
  const float* b_is = (const float*)d_in[2];
  const float* w_ss = (const float*)d_in[3];
  const float* b_ss = (const float*)d_in[4];
  float* outp = (float*)d_out;

  // zph has one extra 512-half bias slot at pos = B*H*W
  const size_t zph_bytes = ((size_t)BB * HH * WW * 512 + 512) * 2;
  const size_t wp_bytes = (size_t)512 * 256 * 2;  // 256 KiB
  const size_t hx_bytes = (size_t)TT * 8 * 4 * 64 * 8;
  const size_t need = zph_bytes + wp_bytes + hx_bytes;

  char* ws = (char*)d_ws;
  if (ws_size >= need) {
    __half* zph = (__half*)ws;
    _Float16* wpp = (_Float16*)(ws + zph_bytes);
    unsigned long long* hx =
        (unsigned long long*)(ws + zph_bytes + wp_bytes);

    prep_zpre<<<dim3(NPREP + 512), 256, 0, stream>>>(x, w_is, b_is, b_ss,
                                                     w_ss, wpp, zph, hx);
    lstm_mfma4w<<<dim3(32), 256, 0, stream>>>(zph, wpp, hx, outp);
  } else {
    // -------- round-1 fallback --------
    const size_t xT_elems = (size_t)BB * HH * WW * 128;
    const size_t st_elems = (size_t)BB * HH * HID;
    const size_t need_xT = (xT_elems + 3 * st_elems) * sizeof(float);
    float* wsf = (float*)d_ws;
    float* xT = nullptr;
    float* st;
    int use_xT = 0;
    if (ws_size >= need_xT) {
      use_xT = 1;
      xT = wsf;
      st = wsf + xT_elems;
    } else {
      st = wsf;
    }
    float* h0 = st;
    float* h1 = st + st_elems;
    float* cb = st + 2 * st_elems;
    hipMemsetAsync(st, 0, 3 * st_elems * sizeof(float), stream);
    if (use_xT) transpose_x<<<dim3(BB * HH), 256, 0, stream>>>(x, xT);
    for (int t = 0; t < TT; t++) {
      float* hp = (t & 1) ? h1 : h0;
      float* hn = (t & 1) ? h0 : h1;
      step_kernel<<<dim3(32, 8), 256, 0, stream>>>(x, xT, use_xT, w_is, b_is,
                                                   w_ss, b_ss, hp, hn, cb, outp,
                                                   t);
    }
  }
}

// Round 8
// 359.541 us; speedup vs baseline: 2.1209x; 1.2109x over previous
//
#include <hip/hip_runtime.h>
#include <hip/hip_fp16.h>
#include <math.h>

// DiagonalLSTM: B=8, Cin=HID=128, H=64, W=64, K=2, T = 2W-1 = 127 steps.
//
// Round 22 design (R19 loop verbatim + zpre folded into lstm prologue):
//   - R21 post-mortem: 4-wave/256-reg variant lost dual-wave latency hiding
//     (1 wave/SIMD exposes every stall; VGPR capped at 256) -> 193->350us.
//     R20 global M-split exchange -> 3.5x regression. The R19 8-wave loop
//     is a local optimum; reverted to it byte-for-byte.
//   - New: zph is block-exclusive (lstm block (rgr,bg) reads exactly the
//     16 (b,r) tiles it owns), so each lstm block computes its own zph in
//     a PROLOGUE: stage x tile -> LDS f16, 8 waves x 4 mt-tiles (w_is
//     A-frags in regs, converted once per block = 8MB total global reads
//     vs 131MB for the 512-block zpre kernel), 64 MFMA/wave/tile, store
//     zph, vmcnt(0) drain + barrier (same-block L2 readback, no grid dep).
//   - prep kernel shrinks to pure-memory 1022 blocks (wp frags, zph bias
//     slot, hx sentinel fill). 2 launches total, lstm starts sooner.
//   - loop: proven R19: z via MFMA C-operand, two independent 4-link MFMA
//     chains, lazy mid-step hx boundary load, LDS-only step barrier,
//     2x-unrolled t-loop, bias folded into zph, incremental pointers,
//     reg-buffered out stores, clamp-free fsig/ftanh.

#define HID 128
#define BB 8
#define HH 64
#define WW 64
#define TT 127

// prep item counts: 131072 (wp frags) + 512 (zph bias) + 130048 (hx fill)
//                 = 261632 = 1022 * 256 exactly
#define NPREP 1022

#define HROW 136  // padded LDS row stride in halfs

typedef _Float16 v8h __attribute__((ext_vector_type(8)));
typedef float v4f __attribute__((ext_vector_type(4)));

#define SENT64 0xFFFFFFFFFFFFFFFFULL  // 4x f16 -NaN (0xFF fill pattern)

__device__ __forceinline__ float fsig(float x) {
  float e = __builtin_amdgcn_exp2f(x * -1.44269504f);
  return __builtin_amdgcn_rcpf(1.f + e);
}
__device__ __forceinline__ float ftanh_(float x) {
  float e = __builtin_amdgcn_exp2f(x * 2.88539009f);
  return __builtin_fmaf(-2.f, __builtin_amdgcn_rcpf(1.f + e), 1.f);
}

// ---- prep kernel: wp frags + zph bias slot + hx sentinel fill ----
__global__ __launch_bounds__(256) void prep_k(
    const float* __restrict__ w_ss, const float* __restrict__ b_is,
    const float* __restrict__ b_ss, _Float16* __restrict__ wp,
    __half* __restrict__ zph, unsigned long long* __restrict__ hx) {
  int idx = blockIdx.x * 256 + threadIdx.x;
  if (idx < 131072) {
    // w_ss -> Wcat(512x256) A-frags: wp[(((mt*8+kt)*64+L)*8+j)]
    int j = idx & 7;
    int L = (idx >> 3) & 63;
    int kt = (idx >> 9) & 7;
    int mt = idx >> 12;
    int O = mt * 16 + (L & 15);
    int k = kt * 32 + ((L >> 4) & 3) * 8 + j;
    float v = (k < 128) ? w_ss[(size_t)O * 256 + k * 2]
                        : w_ss[(size_t)O * 256 + (k - 128) * 2 + 1];
    wp[idx] = (_Float16)v;
  } else if (idx < 131584) {
    // zph bias slot: layout idx2 = (u>>2)*16 + g*4 + (u&3)
    int idx2 = idx - 131072;  // 0..511
    int g = (idx2 >> 2) & 3;
    int u = (idx2 >> 4) * 4 + (idx2 & 3);
    int O = g * 128 + u;
    zph[(size_t)BB * HH * WW * 512 + idx2] = __float2half(b_is[O] + b_ss[O]);
  } else {
    // hx sentinel fill: 260096 u64 as 130048 x 16B
    int j = idx - 131584;
    uint4 s;
    s.x = 0xFFFFFFFFu; s.y = 0xFFFFFFFFu;
    s.z = 0xFFFFFFFFu; s.w = 0xFFFFFFFFu;
    ((uint4*)hx)[j] = s;
  }
}

// Step barrier: LDS-visibility only (no vmcnt drain; see R15 notes).
#define STEP_BARRIER()                                   \
  do {                                                   \
    asm volatile("s_waitcnt lgkmcnt(0)" ::: "memory");   \
    __builtin_amdgcn_s_barrier();                        \
    asm volatile("" ::: "memory");                       \
  } while (0)

#define HPLD(p) __hip_atomic_load((p), __ATOMIC_RELAXED, __HIP_MEMORY_SCOPE_AGENT)

// ---------------- R19 step body (proven) ----------------
#define STEP_BODY(T, RB)                                                       \
  do {                                                                         \
    /* phase 0: chain-0 LDS reads (slot rl) issued ASAP after barrier */       \
    v8h bfr[4];                                                                \
    _Pragma("unroll") for (int kt = 0; kt < 4; kt++)                           \
        bfr[kt] = *(const v8h*)&h_lds[RB][(rl * 2 + bl) * HROW + kt * 32 +     \
                                          quad * 8];                           \
    /* convert zu -> v4f (chain-1 C-operand init) */                           \
    v4f zi[4];                                                                 \
    _Pragma("unroll") for (int g = 0; g < 4; g++)                              \
        _Pragma("unroll") for (int i = 0; i < 4; i++)                          \
        zi[g][i] = __half2float(zu.h[g * 4 + i]);                              \
    /* zp prefetch for T+1 (contiguous 32B; bias slot when out-of-band) */     \
    {                                                                          \
      const uint4* p = (const uint4*)(((unsigned)wn < WW) ? zcur : zbias);     \
      zu.q[0] = p[0];                                                          \
      zu.q[1] = p[1];                                                          \
      wn++;                                                                    \
      zcur += 512;                                                             \
    }                                                                          \
    /* MFMA: two independent 4-link chains; chain-1 accumulates onto z */      \
    v4f acc0[4], acc1[4];                                                      \
    _Pragma("unroll") for (int g = 0; g < 4; g++) {                            \
      acc0[g] = (v4f){0.f, 0.f, 0.f, 0.f};                                     \
      acc1[g] = zi[g];                                                         \
    }                                                                          \
    _Pragma("unroll") for (int kt = 0; kt < 4; kt++) {                         \
      _Pragma("unroll") for (int g = 0; g < 4; g++)                            \
          acc0[g] = __builtin_amdgcn_mfma_f32_16x16x32_f16(                    \
              wfrag[g][kt], bfr[kt], acc0[g], 0, 0, 0);                        \
    }                                                                          \
    _Pragma("unroll") for (int kt = 0; kt < 4; kt++) {                         \
      v8h bf1 = *(const v8h*)&h_lds[RB][((rl + 1) * 2 + bl) * HROW + kt * 32 + \
                                        quad * 8];                             \
      _Pragma("unroll") for (int g = 0; g < 4; g++)                            \
          acc1[g] = __builtin_amdgcn_mfma_f32_16x16x32_f16(                    \
              wfrag[g][4 + kt], bf1, acc1[g], 0, 0, 0);                        \
    }                                                                          \
    /* mid-step hx boundary load (R19 lazy): gates/pack/stores cover it */     \
    unsigned long long pend = 0ull;                                            \
    if (is_cons) pend = HPLD(ca);                                              \
    /* gates (bias pre-folded into zph -> rides in acc1) */                    \
    const int w = (T)-r;                                                       \
    const bool inband = ((unsigned)w < WW);                                    \
    float hv[4];                                                               \
    _Pragma("unroll") for (int rg2 = 0; rg2 < 4; rg2++) {                      \
      float z0 = acc0[0][rg2] + acc1[0][rg2];                                  \
      float z1 = acc0[1][rg2] + acc1[1][rg2];                                  \
      float z2 = acc0[2][rg2] + acc1[2][rg2];                                  \
      float z3 = acc0[3][rg2] + acc1[3][rg2];                                  \
      float iv = fsig(z0);                                                     \
      float fv = fsig(z1);                                                     \
      float ov = fsig(z2);                                                     \
      float gv = ftanh_(z3);                                                   \
      c[rg2] = fv * c[rg2] + iv * gv;                                          \
      hv[rg2] = ov * ftanh_(c[rg2]);                                           \
    }                                                                          \
    /* h(T) -> write-buffer slots 1..8 (LDS, 8B per lane) */                   \
    __half2 plo = __floats2half2_rn(hv[0], hv[1]);                             \
    __half2 phi = __floats2half2_rn(hv[2], hv[3]);                             \
    {                                                                          \
      uint2 pk;                                                                \
      pk.x = *(unsigned*)&plo;                                                 \
      pk.y = *(unsigned*)&phi;                                                 \
      *(uint2*)&h_lds[(RB) ^ 1][((rl + 1) * 2 + bl) * HROW + uq0] = pk;        \
    }                                                                          \
    /* export h(T)[R0+7]: fire-and-forget (data == flag, no drain) */          \
    if (rgr < 7 && l15 >= 14) {                                                \
      unsigned long long pk =                                                  \
          ((unsigned long long)*(unsigned*)&phi << 32) | *(unsigned*)&plo;     \
      __hip_atomic_store(pa_hx, pk, __ATOMIC_RELAXED,                          \
                         __HIP_MEMORY_SCOPE_AGENT);                            \
    }                                                                          \
    pa_hx += 2048;                                                             \
    /* out shift-window; coalesced 16B flush every 4 steps per cell */         \
    _Pragma("unroll") for (int rg2 = 0; rg2 < 4; rg2++) {                      \
      outb[rg2].x = outb[rg2].y;                                               \
      outb[rg2].y = outb[rg2].z;                                               \
      outb[rg2].z = outb[rg2].w;                                               \
      outb[rg2].w = hv[rg2];                                                   \
    }                                                                          \
    if (inband && (w & 3) == 3) {                                              \
      *(float4*)op0 = outb[0];                                                 \
      *(float4*)op1 = outb[1];                                                 \
      *(float4*)op2 = outb[2];                                                 \
      *(float4*)op3 = outb[3];                                                 \
      op0 += 4; op1 += 4; op2 += 4; op3 += 4;                                  \
    }                                                                          \
    /* validate pend (hx[T] = h(T)[R0-1]) -> wb slot 0 */                      \
    if (is_cons) {                                                             \
      while (__ballot(pend == SENT64) != 0ull) {                               \
        __builtin_amdgcn_s_sleep(1);                                           \
        pend = HPLD(ca);                                                       \
      }                                                                        \
      *(unsigned long long*)&h_lds[(RB) ^ 1][(0 * 2 + ebl) * HROW + eu] =      \
          pend;                                                                \
    }                                                                          \
    ca += 2048;                                                                \
    STEP_BARRIER();                                                            \
  } while (0)

__global__ __launch_bounds__(512, 1) void lstm_mfma(
    const __half* __restrict__ zphc, const _Float16* __restrict__ wp,
    unsigned long long* __restrict__ hx,  // [TT][8][4][64], sentinel-filled
    float* __restrict__ out, const float* __restrict__ x,
    const float* __restrict__ w_is, const float* __restrict__ b_is,
    const float* __restrict__ b_ss, __half* __restrict__ zphw) {
  const int blk = blockIdx.x;  // 0..31
  const int rgr = blk >> 2;    // row group 0..7 (rows 8*rgr .. +7)
  const int bg = blk & 3;      // batch group 0..3 (b = 2*bg, 2*bg+1)
  const int R0 = rgr * 8;
  const int tid = threadIdx.x;
  const int wv = tid >> 6;  // wave 0..7
  const int L = tid & 63;
  const int quad = L >> 4;
  const int l15 = L & 15;
  const int rl = l15 >> 1;  // cell row-local 0..7
  const int bl = l15 & 1;   // cell batch-local 0..1
  const int b = bg * 2 + bl;
  const int r = R0 + rl;
  const int uq0 = 16 * wv + quad * 4;     // D-side unit base (+reg)
  const int zoff = (4 * wv + quad) * 16;  // zp contiguous 16-half group

  // double-buffered: slot s holds row R0-1+s (s=0..8), per b-local
  __shared__ _Float16 h_lds[2][9 * 2 * HROW];
  __shared__ _Float16 xt[64][136];  // prologue only
  for (int i = tid; i < (2 * 9 * 2 * HROW) / 2; i += 512)
    ((unsigned*)h_lds)[i] = 0u;

  // ================= prologue: compute this block's zph tiles ============
  // Block (rgr,bg) owns (b in {2bg,2bg+1}) x (r in R0..R0+7) = 16 tiles;
  // these are exactly the zph entries its recurrence loop reads.
  {
    // w_is A-frags: wave owns mt = 4*wv + m (m=0..3); lane L holds
    // w_is[(mt*16+l15)*128 + kt*32 + quad*8 + j]  (same mapping as wp).
    v8h wfr[4][4];
    float4 bvv[4];
#pragma unroll
    for (int m = 0; m < 4; m++) {
      const int mt = 4 * wv + m;
      const int O = mt * 16 + l15;
#pragma unroll
      for (int kt = 0; kt < 4; kt++) {
        const float* p = w_is + (size_t)O * 128 + kt * 32 + quad * 8;
        float4 a = *(const float4*)p;
        float4 b2 = *(const float4*)(p + 4);
        v8h f;
        f[0] = (_Float16)a.x;  f[1] = (_Float16)a.y;
        f[2] = (_Float16)a.z;  f[3] = (_Float16)a.w;
        f[4] = (_Float16)b2.x; f[5] = (_Float16)b2.y;
        f[6] = (_Float16)b2.z; f[7] = (_Float16)b2.w;
        wfr[m][kt] = f;
      }
      const int O4 = mt * 16 + quad * 4;
      float4 bi = *(const float4*)&b_is[O4];
      float4 bs4 = *(const float4*)&b_ss[O4];
      bvv[m] = make_float4(bi.x + bs4.x, bi.y + bs4.y, bi.z + bs4.z,
                           bi.w + bs4.w);
    }

    for (int tt = 0; tt < 16; tt++) {
      const int b2 = bg * 2 + (tt & 1);
      const int r2 = R0 + (tt >> 1);
      __syncthreads();  // xt free (previous tile consumed)
      // stage x(b2,:,r2,:) -> xt transposed [w][c], 512-thread coalesced
      {
        const int cw = tid >> 4;        // 0..31
        const int w4 = (tid & 15) * 4;  // w base
#pragma unroll
        for (int p = 0; p < 4; p++) {
          int cc = p * 32 + cw;
          float4 v =
              *(const float4*)&x[(((size_t)b2 * 128 + cc) * HH + r2) * WW + w4];
          xt[w4 + 0][cc] = (_Float16)v.x;
          xt[w4 + 1][cc] = (_Float16)v.y;
          xt[w4 + 2][cc] = (_Float16)v.z;
          xt[w4 + 3][cc] = (_Float16)v.w;
        }
      }
      __syncthreads();
#pragma unroll
      for (int nt = 0; nt < 4; nt++) {
        v8h bf[4];
#pragma unroll
        for (int kt = 0; kt < 4; kt++)
          bf[kt] = *(const v8h*)&xt[nt * 16 + l15][kt * 32 + quad * 8];
        const size_t pos = ((size_t)b2 * HH + r2) * WW + nt * 16 + l15;
#pragma unroll
        for (int m = 0; m < 4; m++) {
          v4f acc = (v4f){0.f, 0.f, 0.f, 0.f};
#pragma unroll
          for (int kt = 0; kt < 4; kt++)
            acc = __builtin_amdgcn_mfma_f32_16x16x32_f16(wfr[m][kt], bf[kt],
                                                         acc, 0, 0, 0);
          const int mt = 4 * wv + m;
          __half2 lo = __floats2half2_rn(acc[0] + bvv[m].x, acc[1] + bvv[m].y);
          __half2 hi = __floats2half2_rn(acc[2] + bvv[m].z, acc[3] + bvv[m].w);
          uint2 pk;
          pk.x = *(unsigned*)&lo;
          pk.y = *(unsigned*)&hi;
          *(uint2*)&zphw[pos * 512 + ((mt & 7) * 4 + quad) * 16 +
                         (mt >> 3) * 4] = pk;
        }
      }
    }
    // drain zph stores; same-block readback via L2 afterwards
    asm volatile("s_waitcnt vmcnt(0)" ::: "memory");
    __syncthreads();
  }
  const __half* zph = zphc;  // read path (const-qualified)

  // ---- weights as A-fragments, loaded once ----
  v8h wfrag[4][8];
  {
    const v8h* wp8 = (const v8h*)wp;
#pragma unroll
    for (int g = 0; g < 4; g++)
#pragma unroll
      for (int kt = 0; kt < 8; kt++)
        wfrag[g][kt] = wp8[((size_t)((8 * g + wv) * 8 + kt)) * 64 + L];
  }

  float c[4] = {0.f, 0.f, 0.f, 0.f};
  float4 outb[4];  // shift-window out buffer (w-3..w per cell)
#pragma unroll
  for (int i = 0; i < 4; i++) outb[i] = make_float4(0.f, 0.f, 0.f, 0.f);

  const int ebl = L >> 5;       // boundary consumer: b-local
  const int eu = (L & 31) * 4;  // boundary consumer: unit base
  const int exp_idx = bl * 32 + 4 * wv + quad;  // producer slot (l15>=14)

  const bool is_cons = (wv == 0) && (rgr > 0);

  // ---- incremental pointers ----
  const __half* zpp = zph + ((size_t)b * HH + r) * WW * 512 + zoff;
  const __half* zbias = zph + (size_t)BB * HH * WW * 512 + zoff;
  const unsigned long long* ca =
      hx + (((size_t)(rgr > 0 ? rgr - 1 : 0) * 4 + bg) * 64 + L);  // hx[t]
  unsigned long long* pa_hx = hx + (((size_t)rgr * 4 + bg) * 64 + exp_idx);
  float* op0 = out + (((size_t)b * HID + uq0 + 0) * HH + r) * WW;
  float* op1 = out + (((size_t)b * HID + uq0 + 1) * HH + r) * WW;
  float* op2 = out + (((size_t)b * HID + uq0 + 2) * HH + r) * WW;
  float* op3 = out + (((size_t)b * HID + uq0 + 3) * HH + r) * WW;

  // ---- zp for t=0 (w0 = -r: in-band only for r==0) ----
  union ZU {
    uint4 q[2];
    __half h[16];  // h[g*4 + rg2]
  } zu;
  {
    const uint4* p0 = (const uint4*)((r == 0) ? zpp : zbias);
    zu.q[0] = p0[0];
    zu.q[1] = p0[1];
  }
  int wn = 1 - r;  // next-step w
  const __half* zcur = zpp + (ptrdiff_t)wn * 512;

  __syncthreads();

  // 126 = 63x2 steps with static read-buffer index, then epilogue t=126.
  for (int t = 0; t < TT - 1; t += 2) {
    STEP_BODY(t, 0);
    STEP_BODY(t + 1, 1);
  }
  STEP_BODY(TT - 1, 0);
}

// ================= round-1 fallback path (proven correct) =================
__global__ __launch_bounds__(256) void transpose_x(const float* __restrict__ x,
                                                   float* __restrict__ xT) {
  int b = blockIdx.x >> 6;
  int r = blockIdx.x & 63;
  __shared__ float tile[32][65];
  for (int cc = 0; cc < 4; cc++) {
    int cl = threadIdx.x >> 6;
    int w = threadIdx.x & 63;
#pragma unroll
    for (int k = 0; k < 8; k++) {
      int c_loc = k * 4 + cl;
      int c = cc * 32 + c_loc;
      tile[c_loc][w] = x[(((size_t)b * 128 + c) * HH + r) * WW + w];
    }
    __syncthreads();
    int cs = threadIdx.x & 31;
    int wp = threadIdx.x >> 5;
#pragma unroll
    for (int k = 0; k < 8; k++) {
      int w2 = wp * 8 + k;
      xT[(((size_t)b * HH + r) * WW + w2) * 128 + cc * 32 + cs] = tile[cs][w2];
    }
    __syncthreads();
  }
}

__global__ __launch_bounds__(256) void step_kernel(
    const float* __restrict__ x, const float* __restrict__ xT, int use_xT,
    const float* __restrict__ w_is, const float* __restrict__ b_is,
    const float* __restrict__ w_ss, const float* __restrict__ b_ss,
    const float* __restrict__ h_prev, float* __restrict__ h_next,
    float* __restrict__ c_state, float* __restrict__ out, int t) {
  const int rg = blockIdx.x;
  const int q = blockIdx.y;
  const int r0 = rg * 2;
  const int tid = threadIdx.x;
  const int o_loc = tid & 63;
  const int k4 = tid >> 6;
  const int g_ = o_loc >> 4;
  const int u_ = o_loc & 15;
  const int O = g_ * 128 + q * 16 + u_;
  const int i0 = k4 * 32;

  __shared__ __align__(16) float h_in[3][BB][HID];
  __shared__ float zred[16][4][65];

  for (int idx = tid; idx < 3 * BB * HID; idx += 256) {
    int row_sel = idx >> 10;
    int rem = idx & 1023;
    int b = rem >> 7;
    int u = rem & 127;
    int rr = r0 - 1 + row_sel;
    h_in[row_sel][b][u] = (rr >= 0) ? h_prev[((size_t)b * HH + rr) * HID + u] : 0.0f;
  }

  float wr0[32], wr1[32], wz[32];
  {
    const float4* wss4 = (const float4*)(w_ss + ((size_t)O * 128 + i0) * 2);
#pragma unroll
    for (int j = 0; j < 16; j++) {
      float4 v = wss4[j];
      wr0[2 * j] = v.x;
      wr1[2 * j] = v.y;
      wr0[2 * j + 1] = v.z;
      wr1[2 * j + 1] = v.w;
    }
    const float4* wis4 = (const float4*)(w_is + (size_t)O * 128 + i0);
#pragma unroll
    for (int j = 0; j < 8; j++) {
      float4 v = wis4[j];
      wz[4 * j] = v.x;
      wz[4 * j + 1] = v.y;
      wz[4 * j + 2] = v.z;
      wz[4 * j + 3] = v.w;
    }
  }

  __syncthreads();

  float acc[2][BB];
#pragma unroll
  for (int rl = 0; rl < 2; rl++)
#pragma unroll
    for (int b = 0; b < BB; b++) acc[rl][b] = 0.0f;

#pragma unroll
  for (int jb = 0; jb < 8; jb++) {
    int ib = i0 + jb * 4;
#pragma unroll
    for (int b = 0; b < BB; b++) {
      const float4 hm4 = *(const float4*)&h_in[0][b][ib];
      const float4 hc4 = *(const float4*)&h_in[1][b][ib];
      const float4 hp4 = *(const float4*)&h_in[2][b][ib];
      const float* hm = (const float*)&hm4;
      const float* hc = (const float*)&hc4;
      const float* hq = (const float*)&hp4;
#pragma unroll
      for (int jj = 0; jj < 4; jj++) {
        float w0v = wr0[jb * 4 + jj];
        float w1v = wr1[jb * 4 + jj];
        acc[0][b] += w0v * hm[jj] + w1v * hc[jj];
        acc[1][b] += w0v * hc[jj] + w1v * hq[jj];
      }
    }
  }

#pragma unroll
  for (int rl = 0; rl < 2; rl++) {
    int rr = r0 + rl;
    int wcol = t - rr;
    if (wcol >= 0 && wcol < WW) {
      if (use_xT) {
        for (int b = 0; b < BB; b++) {
          const float4* xp =
              (const float4*)(xT + (((size_t)b * HH + rr) * WW + wcol) * 128 + i0);
#pragma unroll
          for (int j = 0; j < 8; j++) {
            float4 v = xp[j];
            acc[rl][b] += wz[4 * j] * v.x + wz[4 * j + 1] * v.y +
                          wz[4 * j + 2] * v.z + wz[4 * j + 3] * v.w;
          }
        }
      } else {
        for (int b = 0; b < BB; b++) {
          const float* xb = x + (((size_t)b * 128 + i0) * HH + rr) * WW + wcol;
#pragma unroll
          for (int j = 0; j < 32; j++) {
            acc[rl][b] += wz[j] * xb[(size_t)j * HH * WW];
          }
        }
      }
    }
  }

#pragma unroll
  for (int rl = 0; rl < 2; rl++)
#pragma unroll
    for (int b = 0; b < BB; b++) zred[rl * 8 + b][k4][o_loc] = acc[rl][b];
  __syncthreads();

  {
    int u = tid >> 4;
    int cell = tid & 15;
    int rl = cell >> 3;
    int b = cell & 7;
    int rr = r0 + rl;
    float z[4];
#pragma unroll
    for (int gg = 0; gg < 4; gg++) {
      int ol = gg * 16 + u;
      float s = zred[cell][0][ol] + zred[cell][1][ol] + zred[cell][2][ol] +
                zred[cell][3][ol];
      int Og = gg * 128 + q * 16 + u;
      z[gg] = s + b_is[Og] + b_ss[Og];
    }
    float iv = 1.0f / (1.0f + expf(-z[0]));
    float fv = 1.0f / (1.0f + expf(-z[1]));
    float ov = 1.0f / (1.0f + expf(-z[2]));
    float gv = tanhf(z[3]);
    int U = q * 16 + u;
    size_t sidx = ((size_t)b * HH + rr) * HID + U;
    float cv = c_state[sidx];
    float cn = fv * cv + iv * gv;
    c_state[sidx] = cn;
    float hn = ov * tanhf(cn);
    h_next[sidx] = hn;
    int wcol = t - rr;
    if (wcol >= 0 && wcol < WW) {
      out[(((size_t)b * HID + U) * HH + rr) * WW + wcol] = hn;
    }
  }
}

extern "C" void kernel_launch(void* const* d_in, const int* in_sizes, int n_in,
                              void* d_out, int out_size, void* d_ws,
                              size_t ws_size, hipStream_t stream) {
  const float* x = (const float*)d_in[0];
  const float* w_is = (const float*)d_in[1];
  const float* b_is = (const float*)d_in[2];
  const float* w_ss = (const float*)d_in[3];
  const float* b_ss = (const float*)d_in[4];
  float* outp = (float*)d_out;

  // zph has one extra 512-half bias slot at pos = B*H*W
  const size_t zph_bytes = ((size_t)BB * HH * WW * 512 + 512) * 2;
  const size_t wp_bytes = (size_t)512 * 256 * 2;  // 256 KiB
  const size_t hx_bytes = (size_t)TT * 8 * 4 * 64 * 8;
  const size_t need = zph_bytes + wp_bytes + hx_bytes;

  char* ws = (char*)d_ws;
  if (ws_size >= need) {
    __half* zph = (__half*)ws;
    _Float16* wpp = (_Float16*)(ws + zph_bytes);
    unsigned long long* hx =
        (unsigned long long*)(ws + zph_bytes + wp_bytes);

    // prep: wp frags + zph bias slot + hx sentinel fill (pure memory)
    prep_k<<<dim3(NPREP), 256, 0, stream>>>(w_ss, b_is, b_ss, wpp, zph, hx);
    // lstm computes its own zph tiles in the prologue
    lstm_mfma<<<dim3(32), 512, 0, stream>>>(zph, wpp, hx, outp, x, w_is,
                                            b_is, b_ss, zph);
  } else {
    // -------- round-1 fallback --------
    const size_t xT_elems = (size_t)BB * HH * WW * 128;
    const size_t st_elems = (size_t)BB * HH * HID;
    const size_t need_xT = (xT_elems + 3 * st_elems) * sizeof(float);
    float* wsf = (float*)d_ws;
    float* xT = nullptr;
    float* st;
    int use_xT = 0;
    if (ws_size >= need_xT) {
      use_xT = 1;
      xT = wsf;
      st = wsf + xT_elems;
    } else {
      st = wsf;
    }
    float* h0 = st;
    float* h1 = st + st_elems;
    float* cb = st + 2 * st_elems;
    hipMemsetAsync(st, 0, 3 * st_elems * sizeof(float), stream);
    if (use_xT) transpose_x<<<dim3(BB * HH), 256, 0, stream>>>(x, xT);
    for (int t = 0; t < TT; t++) {
      float* hp = (t & 1) ? h1 : h0;
      float* hn = (t & 1) ? h0 : h1;
      step_kernel<<<dim3(32, 8), 256, 0, stream>>>(x, xT, use_xT, w_is, b_is,
                                                   w_ss, b_ss, hp, hn, cb, outp,
                                                   t);
    }
  }
}

// Round 9
// 322.046 us; speedup vs baseline: 2.3678x; 1.1164x over previous
//
#include <hip/hip_runtime.h>
#include <hip/hip_fp16.h>
#include <math.h>

// DiagonalLSTM: B=8, Cin=HID=128, H=64, W=64, K=2, T = 2W-1 = 127 steps.
//
// Round 23 design (R19 loop + zpre OVERLAPPED in the same launch):
//   - R22 post-mortem: zpre in the 32-block prologue = same work on 8x
//     fewer CUs -> +107us serial. Decomposition: fixed overhead ~59us,
//     zpre-as-wide-kernel ~39us, lstm loop 193us.
//   - Fix: ONE fused launch, 544 blocks x 512 thr. Blocks 0..31 = R19
//     lstm (loop byte-identical). Blocks 32..543 = zpre, one (b,r) tile
//     each (R22-verified math), mapped r-major (i>>3 = r) so low-r tiles
//     finish in the first dispatch round, matching lstm's consumption
//     order (block rgr needs r=8rgr tiles at ~rgr*12us).
//   - Sync: 512 per-tile flags. Producer: __syncthreads (drains vmcnt)
//     -> agent release fence -> relaxed flag store. Consumer lane: at its
//     FIRST in-band zp prefetch (t=r-1), relaxed spin + acquire fence,
//     then plain zph loads forever (zero steady-state cost). Correct for
//     any dispatch order; zpre blocks never wait -> no deadlock.
//   - prep_k (launch 1): wp frags + zph bias slot + zflag=0 + hx fill.
//   - loop: proven R19: z via MFMA C-operand, two independent 4-link MFMA
//     chains, lazy mid-step hx boundary load, LDS-only step barrier,
//     2x-unrolled t-loop, bias folded into zph, incremental pointers,
//     reg-buffered out stores, clamp-free fsig/ftanh.

#define HID 128
#define BB 8
#define HH 64
#define WW 64
#define TT 127

// prep items: 131072 wp | 512 bias | 512 zflag | 130048 hx-uint4
//           = 262144 = 1024 * 256 exactly
#define NPREP 1024

#define HROW 136  // padded LDS row stride in halfs

typedef _Float16 v8h __attribute__((ext_vector_type(8)));
typedef float v4f __attribute__((ext_vector_type(4)));

#define SENT64 0xFFFFFFFFFFFFFFFFULL  // 4x f16 -NaN (0xFF fill pattern)

__device__ __forceinline__ float fsig(float x) {
  float e = __builtin_amdgcn_exp2f(x * -1.44269504f);
  return __builtin_amdgcn_rcpf(1.f + e);
}
__device__ __forceinline__ float ftanh_(float x) {
  float e = __builtin_amdgcn_exp2f(x * 2.88539009f);
  return __builtin_fmaf(-2.f, __builtin_amdgcn_rcpf(1.f + e), 1.f);
}

// ---- prep kernel: wp frags + zph bias slot + zflag init + hx fill ----
__global__ __launch_bounds__(256) void prep_k(
    const float* __restrict__ w_ss, const float* __restrict__ b_is,
    const float* __restrict__ b_ss, _Float16* __restrict__ wp,
    __half* __restrict__ zph, unsigned* __restrict__ zflag,
    unsigned long long* __restrict__ hx) {
  int idx = blockIdx.x * 256 + threadIdx.x;
  if (idx < 131072) {
    // w_ss -> Wcat(512x256) A-frags: wp[(((mt*8+kt)*64+L)*8+j)]
    int j = idx & 7;
    int L = (idx >> 3) & 63;
    int kt = (idx >> 9) & 7;
    int mt = idx >> 12;
    int O = mt * 16 + (L & 15);
    int k = kt * 32 + ((L >> 4) & 3) * 8 + j;
    float v = (k < 128) ? w_ss[(size_t)O * 256 + k * 2]
                        : w_ss[(size_t)O * 256 + (k - 128) * 2 + 1];
    wp[idx] = (_Float16)v;
  } else if (idx < 131584) {
    // zph bias slot: layout idx2 = (u>>2)*16 + g*4 + (u&3)
    int idx2 = idx - 131072;  // 0..511
    int g = (idx2 >> 2) & 3;
    int u = (idx2 >> 4) * 4 + (idx2 & 3);
    int O = g * 128 + u;
    zph[(size_t)BB * HH * WW * 512 + idx2] = __float2half(b_is[O] + b_ss[O]);
  } else if (idx < 132096) {
    zflag[idx - 131584] = 0u;
  } else {
    // hx sentinel fill: 260096 u64 as 130048 x 16B
    int j = idx - 132096;
    uint4 s;
    s.x = 0xFFFFFFFFu; s.y = 0xFFFFFFFFu;
    s.z = 0xFFFFFFFFu; s.w = 0xFFFFFFFFu;
    ((uint4*)hx)[j] = s;
  }
}

// Step barrier: LDS-visibility only (no vmcnt drain; see R15 notes).
#define STEP_BARRIER()                                   \
  do {                                                   \
    asm volatile("s_waitcnt lgkmcnt(0)" ::: "memory");   \
    __builtin_amdgcn_s_barrier();                        \
    asm volatile("" ::: "memory");                       \
  } while (0)

#define HPLD(p) __hip_atomic_load((p), __ATOMIC_RELAXED, __HIP_MEMORY_SCOPE_AGENT)

// ---------------- R19 step body + one-time lazy zflag wait ----------------
#define STEP_BODY(T, RB)                                                       \
  do {                                                                         \
    /* phase 0: chain-0 LDS reads (slot rl) issued ASAP after barrier */       \
    v8h bfr[4];                                                                \
    _Pragma("unroll") for (int kt = 0; kt < 4; kt++)                           \
        bfr[kt] = *(const v8h*)&h_lds[RB][(rl * 2 + bl) * HROW + kt * 32 +     \
                                          quad * 8];                           \
    /* convert zu -> v4f (chain-1 C-operand init) */                           \
    v4f zi[4];                                                                 \
    _Pragma("unroll") for (int g = 0; g < 4; g++)                              \
        _Pragma("unroll") for (int i = 0; i < 4; i++)                          \
        zi[g][i] = __half2float(zu.h[g * 4 + i]);                              \
    /* zp prefetch for T+1; one-time flag wait at first in-band prefetch */    \
    {                                                                          \
      if (!zdone && (unsigned)wn < WW) {                                       \
        while (__hip_atomic_load(zf, __ATOMIC_RELAXED,                         \
                                 __HIP_MEMORY_SCOPE_AGENT) == 0u)              \
          __builtin_amdgcn_s_sleep(2);                                         \
        __builtin_amdgcn_fence(__ATOMIC_ACQUIRE, "agent");                     \
        zdone = true;                                                          \
      }                                                                        \
      const uint4* p = (const uint4*)(((unsigned)wn < WW) ? zcur : zbias);     \
      zu.q[0] = p[0];                                                          \
      zu.q[1] = p[1];                                                          \
      wn++;                                                                    \
      zcur += 512;                                                             \
    }                                                                          \
    /* MFMA: two independent 4-link chains; chain-1 accumulates onto z */      \
    v4f acc0[4], acc1[4];                                                      \
    _Pragma("unroll") for (int g = 0; g < 4; g++) {                            \
      acc0[g] = (v4f){0.f, 0.f, 0.f, 0.f};                                     \
      acc1[g] = zi[g];                                                         \
    }                                                                          \
    _Pragma("unroll") for (int kt = 0; kt < 4; kt++) {                         \
      _Pragma("unroll") for (int g = 0; g < 4; g++)                            \
          acc0[g] = __builtin_amdgcn_mfma_f32_16x16x32_f16(                    \
              wfrag[g][kt], bfr[kt], acc0[g], 0, 0, 0);                        \
    }                                                                          \
    _Pragma("unroll") for (int kt = 0; kt < 4; kt++) {                         \
      v8h bf1 = *(const v8h*)&h_lds[RB][((rl + 1) * 2 + bl) * HROW + kt * 32 + \
                                        quad * 8];                             \
      _Pragma("unroll") for (int g = 0; g < 4; g++)                            \
          acc1[g] = __builtin_amdgcn_mfma_f32_16x16x32_f16(                    \
              wfrag[g][4 + kt], bf1, acc1[g], 0, 0, 0);                        \
    }                                                                          \
    /* mid-step hx boundary load (R19 lazy): gates/pack/stores cover it */     \
    unsigned long long pend = 0ull;                                            \
    if (is_cons) pend = HPLD(ca);                                              \
    /* gates (bias pre-folded into zph -> rides in acc1) */                    \
    const int w = (T)-r;                                                       \
    const bool inband = ((unsigned)w < WW);                                    \
    float hv[4];                                                               \
    _Pragma("unroll") for (int rg2 = 0; rg2 < 4; rg2++) {                      \
      float z0 = acc0[0][rg2] + acc1[0][rg2];                                  \
      float z1 = acc0[1][rg2] + acc1[1][rg2];                                  \
      float z2 = acc0[2][rg2] + acc1[2][rg2];                                  \
      float z3 = acc0[3][rg2] + acc1[3][rg2];                                  \
      float iv = fsig(z0);                                                     \
      float fv = fsig(z1);                                                     \
      float ov = fsig(z2);                                                     \
      float gv = ftanh_(z3);                                                   \
      c[rg2] = fv * c[rg2] + iv * gv;                                          \
      hv[rg2] = ov * ftanh_(c[rg2]);                                           \
    }                                                                          \
    /* h(T) -> write-buffer slots 1..8 (LDS, 8B per lane) */                   \
    __half2 plo = __floats2half2_rn(hv[0], hv[1]);                             \
    __half2 phi = __floats2half2_rn(hv[2], hv[3]);                             \
    {                                                                          \
      uint2 pk;                                                                \
      pk.x = *(unsigned*)&plo;                                                 \
      pk.y = *(unsigned*)&phi;                                                 \
      *(uint2*)&h_lds[(RB) ^ 1][((rl + 1) * 2 + bl) * HROW + uq0] = pk;        \
    }                                                                          \
    /* export h(T)[R0+7]: fire-and-forget (data == flag, no drain) */          \
    if (rgr < 7 && l15 >= 14) {                                                \
      unsigned long long pk =                                                  \
          ((unsigned long long)*(unsigned*)&phi << 32) | *(unsigned*)&plo;     \
      __hip_atomic_store(pa_hx, pk, __ATOMIC_RELAXED,                          \
                         __HIP_MEMORY_SCOPE_AGENT);                            \
    }                                                                          \
    pa_hx += 2048;                                                             \
    /* out shift-window; coalesced 16B flush every 4 steps per cell */         \
    _Pragma("unroll") for (int rg2 = 0; rg2 < 4; rg2++) {                      \
      outb[rg2].x = outb[rg2].y;                                               \
      outb[rg2].y = outb[rg2].z;                                               \
      outb[rg2].z = outb[rg2].w;                                               \
      outb[rg2].w = hv[rg2];                                                   \
    }                                                                          \
    if (inband && (w & 3) == 3) {                                              \
      *(float4*)op0 = outb[0];                                                 \
      *(float4*)op1 = outb[1];                                                 \
      *(float4*)op2 = outb[2];                                                 \
      *(float4*)op3 = outb[3];                                                 \
      op0 += 4; op1 += 4; op2 += 4; op3 += 4;                                  \
    }                                                                          \
    /* validate pend (hx[T] = h(T)[R0-1]) -> wb slot 0 */                      \
    if (is_cons) {                                                             \
      while (__ballot(pend == SENT64) != 0ull) {                               \
        __builtin_amdgcn_s_sleep(1);                                           \
        pend = HPLD(ca);                                                       \
      }                                                                        \
      *(unsigned long long*)&h_lds[(RB) ^ 1][(0 * 2 + ebl) * HROW + eu] =      \
          pend;                                                                \
    }                                                                          \
    ca += 2048;                                                                \
    STEP_BARRIER();                                                            \
  } while (0)

// ---- fused kernel: blocks 0..31 lstm, blocks 32..543 zpre tiles ----
__global__ __launch_bounds__(512, 1) void fused(
    const __half* __restrict__ zph, const _Float16* __restrict__ wp,
    unsigned long long* __restrict__ hx, float* __restrict__ out,
    const float* __restrict__ x, const float* __restrict__ w_is,
    const float* __restrict__ b_is, const float* __restrict__ b_ss,
    unsigned* __restrict__ zflag, __half* __restrict__ zphw) {
  __shared__ _Float16 h_lds[2][9 * 2 * HROW];
  __shared__ _Float16 xt[64][136];

  const int blk = blockIdx.x;
  const int tid = threadIdx.x;
  const int L = tid & 63;
  const int quad = L >> 4;
  const int l15 = L & 15;

  if (blk >= 32) {
    // ================= zpre block: one (b,r) tile =================
    const int i = blk - 32;  // 0..511, r-major so low r completes first
    const int r = i >> 3;
    const int b = i & 7;
    const int wv8 = tid >> 6;  // 0..7; wave owns mt = 4*wv8 + m

    // stage x(b,:,r,:) -> xt transposed [w][c], 512-thread coalesced
    {
      const int cw = tid >> 4;        // 0..31
      const int w4 = (tid & 15) * 4;  // w base
#pragma unroll
      for (int p = 0; p < 4; p++) {
        int cc = p * 32 + cw;
        float4 v =
            *(const float4*)&x[(((size_t)b * 128 + cc) * HH + r) * WW + w4];
        xt[w4 + 0][cc] = (_Float16)v.x;
        xt[w4 + 1][cc] = (_Float16)v.y;
        xt[w4 + 2][cc] = (_Float16)v.z;
        xt[w4 + 3][cc] = (_Float16)v.w;
      }
    }

    // w_is A-frags (R22-verified mapping): lane L of tile (mt,kt) holds
    // w_is[(mt*16+l15)*128 + kt*32 + quad*8 + j]
    v8h wfr[4][4];
    float4 bvv[4];
#pragma unroll
    for (int m = 0; m < 4; m++) {
      const int mt = 4 * wv8 + m;
      const int O = mt * 16 + l15;
#pragma unroll
      for (int kt = 0; kt < 4; kt++) {
        const float* p = w_is + (size_t)O * 128 + kt * 32 + quad * 8;
        float4 a = *(const float4*)p;
        float4 b2 = *(const float4*)(p + 4);
        v8h f;
        f[0] = (_Float16)a.x;  f[1] = (_Float16)a.y;
        f[2] = (_Float16)a.z;  f[3] = (_Float16)a.w;
        f[4] = (_Float16)b2.x; f[5] = (_Float16)b2.y;
        f[6] = (_Float16)b2.z; f[7] = (_Float16)b2.w;
        wfr[m][kt] = f;
      }
      const int O4 = mt * 16 + quad * 4;
      float4 bi = *(const float4*)&b_is[O4];
      float4 bs4 = *(const float4*)&b_ss[O4];
      bvv[m] = make_float4(bi.x + bs4.x, bi.y + bs4.y, bi.z + bs4.z,
                           bi.w + bs4.w);
    }

    __syncthreads();

#pragma unroll
    for (int nt = 0; nt < 4; nt++) {
      v8h bf[4];
#pragma unroll
      for (int kt = 0; kt < 4; kt++)
        bf[kt] = *(const v8h*)&xt[nt * 16 + l15][kt * 32 + quad * 8];
      const size_t pos = ((size_t)b * HH + r) * WW + nt * 16 + l15;
#pragma unroll
      for (int m = 0; m < 4; m++) {
        v4f acc = (v4f){0.f, 0.f, 0.f, 0.f};
#pragma unroll
        for (int kt = 0; kt < 4; kt++)
          acc = __builtin_amdgcn_mfma_f32_16x16x32_f16(wfr[m][kt], bf[kt], acc,
                                                       0, 0, 0);
        const int mt = 4 * wv8 + m;
        __half2 lo = __floats2half2_rn(acc[0] + bvv[m].x, acc[1] + bvv[m].y);
        __half2 hi = __floats2half2_rn(acc[2] + bvv[m].z, acc[3] + bvv[m].w);
        uint2 pk;
        pk.x = *(unsigned*)&lo;
        pk.y = *(unsigned*)&hi;
        *(uint2*)&zphw[pos * 512 + ((mt & 7) * 4 + quad) * 16 +
                       (mt >> 3) * 4] = pk;
      }
    }

    // publish: drain all waves' stores (syncthreads waits vmcnt(0)),
    // release-fence (L2 writeback), then coherent flag store.
    __syncthreads();
    if (tid == 0) {
      __builtin_amdgcn_fence(__ATOMIC_RELEASE, "agent");
      __hip_atomic_store(&zflag[i], 1u, __ATOMIC_RELAXED,
                         __HIP_MEMORY_SCOPE_AGENT);
    }
    return;
  }

  // ================= lstm block (R19, byte-identical loop) =================
  const int rgr = blk >> 2;
  const int bg = blk & 3;
  const int R0 = rgr * 8;
  const int wv = tid >> 6;
  const int rl = l15 >> 1;
  const int bl = l15 & 1;
  const int b = bg * 2 + bl;
  const int r = R0 + rl;
  const int uq0 = 16 * wv + quad * 4;
  const int zoff = (4 * wv + quad) * 16;

  for (int i = tid; i < (2 * 9 * 2 * HROW) / 2; i += 512)
    ((unsigned*)h_lds)[i] = 0u;

  // ---- weights as A-fragments, loaded once ----
  v8h wfrag[4][8];
  {
    const v8h* wp8 = (const v8h*)wp;
#pragma unroll
    for (int g = 0; g < 4; g++)
#pragma unroll
      for (int kt = 0; kt < 8; kt++)
        wfrag[g][kt] = wp8[((size_t)((8 * g + wv) * 8 + kt)) * 64 + L];
  }

  float c[4] = {0.f, 0.f, 0.f, 0.f};
  float4 outb[4];
#pragma unroll
  for (int i = 0; i < 4; i++) outb[i] = make_float4(0.f, 0.f, 0.f, 0.f);

  const int ebl = L >> 5;
  const int eu = (L & 31) * 4;
  const int exp_idx = bl * 32 + 4 * wv + quad;

  const bool is_cons = (wv == 0) && (rgr > 0);

  // ---- incremental pointers ----
  const __half* zpp = zph + ((size_t)b * HH + r) * WW * 512 + zoff;
  const __half* zbias = zph + (size_t)BB * HH * WW * 512 + zoff;
  const unsigned long long* ca =
      hx + (((size_t)(rgr > 0 ? rgr - 1 : 0) * 4 + bg) * 64 + L);
  unsigned long long* pa_hx = hx + (((size_t)rgr * 4 + bg) * 64 + exp_idx);
  float* op0 = out + (((size_t)b * HID + uq0 + 0) * HH + r) * WW;
  float* op1 = out + (((size_t)b * HID + uq0 + 1) * HH + r) * WW;
  float* op2 = out + (((size_t)b * HID + uq0 + 2) * HH + r) * WW;
  float* op3 = out + (((size_t)b * HID + uq0 + 3) * HH + r) * WW;

  // ---- zph readiness flag for this lane's (b,r) tile ----
  unsigned* zf = &zflag[r * 8 + b];
  bool zdone = false;

  // ---- zp for t=0 (w0 = -r: in-band only for r==0) ----
  union ZU {
    uint4 q[2];
    __half h[16];
  } zu;
  {
    if (r == 0) {  // r==0 lanes read real zph at t=0: wait for their tile
      while (__hip_atomic_load(zf, __ATOMIC_RELAXED,
                               __HIP_MEMORY_SCOPE_AGENT) == 0u)
        __builtin_amdgcn_s_sleep(2);
      __builtin_amdgcn_fence(__ATOMIC_ACQUIRE, "agent");
      zdone = true;
    }
    const uint4* p0 = (const uint4*)((r == 0) ? zpp : zbias);
    zu.q[0] = p0[0];
    zu.q[1] = p0[1];
  }
  int wn = 1 - r;
  const __half* zcur = zpp + (ptrdiff_t)wn * 512;

  __syncthreads();

  // 126 = 63x2 steps with static read-buffer index, then epilogue t=126.
  for (int t = 0; t < TT - 1; t += 2) {
    STEP_BODY(t, 0);
    STEP_BODY(t + 1, 1);
  }
  STEP_BODY(TT - 1, 0);
}

// ================= round-1 fallback path (proven correct) =================
__global__ __launch_bounds__(256) void transpose_x(const float* __restrict__ x,
                                                   float* __restrict__ xT) {
  int b = blockIdx.x >> 6;
  int r = blockIdx.x & 63;
  __shared__ float tile[32][65];
  for (int cc = 0; cc < 4; cc++) {
    int cl = threadIdx.x >> 6;
    int w = threadIdx.x & 63;
#pragma unroll
    for (int k = 0; k < 8; k++) {
      int c_loc = k * 4 + cl;
      int c = cc * 32 + c_loc;
      tile[c_loc][w] = x[(((size_t)b * 128 + c) * HH + r) * WW + w];
    }
    __syncthreads();
    int cs = threadIdx.x & 31;
    int wp = threadIdx.x >> 5;
#pragma unroll
    for (int k = 0; k < 8; k++) {
      int w2 = wp * 8 + k;
      xT[(((size_t)b * HH + r) * WW + w2) * 128 + cc * 32 + cs] = tile[cs][w2];
    }
    __syncthreads();
  }
}

__global__ __launch_bounds__(256) void step_kernel(
    const float* __restrict__ x, const float* __restrict__ xT, int use_xT,
    const float* __restrict__ w_is, const float* __restrict__ b_is,
    const float* __restrict__ w_ss, const float* __restrict__ b_ss,
    const float* __restrict__ h_prev, float* __restrict__ h_next,
    float* __restrict__ c_state, float* __restrict__ out, int t) {
  const int rg = blockIdx.x;
  const int q = blockIdx.y;
  const int r0 = rg * 2;
  const int tid = threadIdx.x;
  const int o_loc = tid & 63;
  const int k4 = tid >> 6;
  const int g_ = o_loc >> 4;
  const int u_ = o_loc & 15;
  const int O = g_ * 128 + q * 16 + u_;
  const int i0 = k4 * 32;

  __shared__ __align__(16) float h_in[3][BB][HID];
  __shared__ float zred[16][4][65];

  for (int idx = tid; idx < 3 * BB * HID; idx += 256) {
    int row_sel = idx >> 10;
    int rem = idx & 1023;
    int b = rem >> 7;
    int u = rem & 127;
    int rr = r0 - 1 + row_sel;
    h_in[row_sel][b][u] = (rr >= 0) ? h_prev[((size_t)b * HH + rr) * HID + u] : 0.0f;
  }

  float wr0[32], wr1[32], wz[32];
  {
    const float4* wss4 = (const float4*)(w_ss + ((size_t)O * 128 + i0) * 2);
#pragma unroll
    for (int j = 0; j < 16; j++) {
      float4 v = wss4[j];
      wr0[2 * j] = v.x;
      wr1[2 * j] = v.y;
      wr0[2 * j + 1] = v.z;
      wr1[2 * j + 1] = v.w;
    }
    const float4* wis4 = (const float4*)(w_is + (size_t)O * 128 + i0);
#pragma unroll
    for (int j = 0; j < 8; j++) {
      float4 v = wis4[j];
      wz[4 * j] = v.x;
      wz[4 * j + 1] = v.y;
      wz[4 * j + 2] = v.z;
      wz[4 * j + 3] = v.w;
    }
  }

  __syncthreads();

  float acc[2][BB];
#pragma unroll
  for (int rl = 0; rl < 2; rl++)
#pragma unroll
    for (int b = 0; b < BB; b++) acc[rl][b] = 0.0f;

#pragma unroll
  for (int jb = 0; jb < 8; jb++) {
    int ib = i0 + jb * 4;
#pragma unroll
    for (int b = 0; b < BB; b++) {
      const float4 hm4 = *(const float4*)&h_in[0][b][ib];
      const float4 hc4 = *(const float4*)&h_in[1][b][ib];
      const float4 hp4 = *(const float4*)&h_in[2][b][ib];
      const float* hm = (const float*)&hm4;
      const float* hc = (const float*)&hc4;
      const float* hq = (const float*)&hp4;
#pragma unroll
      for (int jj = 0; jj < 4; jj++) {
        float w0v = wr0[jb * 4 + jj];
        float w1v = wr1[jb * 4 + jj];
        acc[0][b] += w0v * hm[jj] + w1v * hc[jj];
        acc[1][b] += w0v * hc[jj] + w1v * hq[jj];
      }
    }
  }

#pragma unroll
  for (int rl = 0; rl < 2; rl++) {
    int rr = r0 + rl;
    int wcol = t - rr;
    if (wcol >= 0 && wcol < WW) {
      if (use_xT) {
        for (int b = 0; b < BB; b++) {
          const float4* xp =
              (const float4*)(xT + (((size_t)b * HH + rr) * WW + wcol) * 128 + i0);
#pragma unroll
          for (int j = 0; j < 8; j++) {
            float4 v = xp[j];
            acc[rl][b] += wz[4 * j] * v.x + wz[4 * j + 1] * v.y +
                          wz[4 * j + 2] * v.z + wz[4 * j + 3] * v.w;
          }
        }
      } else {
        for (int b = 0; b < BB; b++) {
          const float* xb = x + (((size_t)b * 128 + i0) * HH + rr) * WW + wcol;
#pragma unroll
          for (int j = 0; j < 32; j++) {
            acc[rl][b] += wz[j] * xb[(size_t)j * HH * WW];
          }
        }
      }
    }
  }

#pragma unroll
  for (int rl = 0; rl < 2; rl++)
#pragma unroll
    for (int b = 0; b < BB; b++) zred[rl * 8 + b][k4][o_loc] = acc[rl][b];
  __syncthreads();

  {
    int u = tid >> 4;
    int cell = tid & 15;
    int rl = cell >> 3;
    int b = cell & 7;
    int rr = r0 + rl;
    float z[4];
#pragma unroll
    for (int gg = 0; gg < 4; gg++) {
      int ol = gg * 16 + u;
      float s = zred[cell][0][ol] + zred[cell][1][ol] + zred[cell][2][ol] +
                zred[cell][3][ol];
      int Og = gg * 128 + q * 16 + u;
      z[gg] = s + b_is[Og] + b_ss[Og];
    }
    float iv = 1.0f / (1.0f + expf(-z[0]));
    float fv = 1.0f / (1.0f + expf(-z[1]));
    float ov = 1.0f / (1.0f + expf(-z[2]));
    float gv = tanhf(z[3]);
    int U = q * 16 + u;
    size_t sidx = ((size_t)b * HH + rr) * HID + U;
    float cv = c_state[sidx];
    float cn = fv * cv + iv * gv;
    c_state[sidx] = cn;
    float hn = ov * tanhf(cn);
    h_next[sidx] = hn;
    int wcol = t - rr;
    if (wcol >= 0 && wcol < WW) {
      out[(((size_t)b * HID + U) * HH + rr) * WW + wcol] = hn;
    }
  }
}

extern "C" void kernel_launch(void* const* d_in, const int* in_sizes, int n_in,
                              void* d_out, int out_size, void* d_ws,
                              size_t ws_size, hipStream_t stream) {
  const float* x = (const float*)d_in[0];
  const float* w_is = (const float*)d_in[1];
  const float* b_is = (const float*)d_in[2];
  const float* w_ss = (const float*)d_in[3];
  const float* b_ss = (const float*)d_in[4];
  float* outp = (float*)d_out;

  // zph has one extra 512-half bias slot at pos = B*H*W
  const size_t zph_bytes = ((size_t)BB * HH * WW * 512 + 512) * 2;
  const size_t wp_bytes = (size_t)512 * 256 * 2;  // 256 KiB
  const size_t hx_bytes = (size_t)TT * 8 * 4 * 64 * 8;
  const size_t zflag_bytes = 512 * sizeof(unsigned);
  const size_t need = zph_bytes + wp_bytes + hx_bytes + zflag_bytes;

  char* ws = (char*)d_ws;
  if (ws_size >= need) {
    __half* zph = (__half*)ws;
    _Float16* wpp = (_Float16*)(ws + zph_bytes);
    unsigned long long* hx =
        (unsigned long long*)(ws + zph_bytes + wp_bytes);
    unsigned* zflag = (unsigned*)(ws + zph_bytes + wp_bytes + hx_bytes);

    // launch 1: wp frags + zph bias slot + zflag=0 + hx sentinel fill
    prep_k<<<dim3(NPREP), 256, 0, stream>>>(w_ss, b_is, b_ss, wpp, zph,
                                            zflag, hx);
    // launch 2: fused lstm (blocks 0..31) + zpre tiles (blocks 32..543)
    fused<<<dim3(544), 512, 0, stream>>>(zph, wpp, hx, outp, x, w_is, b_is,
                                         b_ss, zflag, zph);
  } else {
    // -------- round-1 fallback --------
    const size_t xT_elems = (size_t)BB * HH * WW * 128;
    const size_t st_elems = (size_t)BB * HH * HID;
    const size_t need_xT = (xT_elems + 3 * st_elems) * sizeof(float);
    float* wsf = (float*)d_ws;
    float* xT = nullptr;
    float* st;
    int use_xT = 0;
    if (ws_size >= need_xT) {
      use_xT = 1;
      xT = wsf;
      st = wsf + xT_elems;
    } else {
      st = wsf;
    }
    float* h0 = st;
    float* h1 = st + st_elems;
    float* cb = st + 2 * st_elems;
    hipMemsetAsync(st, 0, 3 * st_elems * sizeof(float), stream);
    if (use_xT) transpose_x<<<dim3(BB * HH), 256, 0, stream>>>(x, xT);
    for (int t = 0; t < TT; t++) {
      float* hp = (t & 1) ? h1 : h0;
      float* hn = (t & 1) ? h0 : h1;
      step_kernel<<<dim3(32, 8), 256, 0, stream>>>(x, xT, use_xT, w_is, b_is,
                                                   w_ss, b_ss, hp, hn, cb, outp,
                                                   t);
    }
  }
}